// Round 14
// baseline (230.636 us; speedup 1.0000x reference)
//
#include <hip/hip_runtime.h>
#include <hip/hip_fp16.h>
#include <stdint.h>
#include <math.h>

// Problem constants
#define NROWS 2048
#define SEQ   128
#define EMB   512
#define HID   1024
#define VOCAB 50257
#define GR    4      // fallback gather: rows per block
#define NSPEC 8      // speculative Wood iterations
#define NCHUNK 8     // vocab chunks (one per XCD)

typedef _Float16 f16x4 __attribute__((ext_vector_type(4)));
typedef float    f32x4 __attribute__((ext_vector_type(4)));

// ---------------------------------------------------------------------------
// threefry2x32 (JAX PRNG), exact
// ---------------------------------------------------------------------------
struct U2 { uint32_t x, y; };

__device__ __forceinline__ uint32_t rotl32(uint32_t v, int r) {
  return (v << r) | (v >> (32 - r));
}

__device__ __forceinline__ U2 tf2x32(U2 key, uint32_t x0, uint32_t x1) {
  uint32_t ks0 = key.x, ks1 = key.y;
  uint32_t ks2 = ks0 ^ ks1 ^ 0x1BD11BDAu;
  x0 += ks0; x1 += ks1;
  x0 += x1; x1 = rotl32(x1, 13); x1 ^= x0;
  x0 += x1; x1 = rotl32(x1, 15); x1 ^= x0;
  x0 += x1; x1 = rotl32(x1, 26); x1 ^= x0;
  x0 += x1; x1 = rotl32(x1, 6);  x1 ^= x0;
  x0 += ks1; x1 += ks2 + 1u;
  x0 += x1; x1 = rotl32(x1, 17); x1 ^= x0;
  x0 += x1; x1 = rotl32(x1, 29); x1 ^= x0;
  x0 += x1; x1 = rotl32(x1, 16); x1 ^= x0;
  x0 += x1; x1 = rotl32(x1, 24); x1 ^= x0;
  x0 += ks2; x1 += ks0 + 2u;
  x0 += x1; x1 = rotl32(x1, 13); x1 ^= x0;
  x0 += x1; x1 = rotl32(x1, 15); x1 ^= x0;
  x0 += x1; x1 = rotl32(x1, 26); x1 ^= x0;
  x0 += x1; x1 = rotl32(x1, 6);  x1 ^= x0;
  x0 += ks0; x1 += ks1 + 3u;
  x0 += x1; x1 = rotl32(x1, 17); x1 ^= x0;
  x0 += x1; x1 = rotl32(x1, 29); x1 ^= x0;
  x0 += x1; x1 = rotl32(x1, 16); x1 ^= x0;
  x0 += x1; x1 = rotl32(x1, 24); x1 ^= x0;
  x0 += ks1; x1 += ks2 + 4u;
  x0 += x1; x1 = rotl32(x1, 13); x1 ^= x0;
  x0 += x1; x1 = rotl32(x1, 15); x1 ^= x0;
  x0 += x1; x1 = rotl32(x1, 26); x1 ^= x0;
  x0 += x1; x1 = rotl32(x1, 6);  x1 ^= x0;
  x0 += ks2; x1 += ks0 + 5u;
  U2 r; r.x = x0; r.y = x1; return r;
}

__device__ __forceinline__ U2 tf_subkey(U2 key, uint32_t i) { return tf2x32(key, 0u, i); }
__device__ __forceinline__ uint32_t tf_bits32(U2 key, uint32_t idx) {
  U2 r = tf2x32(key, 0u, idx);
  return r.x ^ r.y;
}

__device__ __forceinline__ float unit_from_bits(uint32_t b) {
  uint32_t fb = (b >> 9) | 0x3f800000u;
  return __uint_as_float(fb) - 1.0f;
}

__device__ __forceinline__ float f32_log(float x)  { return (float)log((double)x); }
__device__ __forceinline__ float f32_exp(float x)  { return (float)exp((double)x); }
__device__ __forceinline__ float f32_log1p(float x){ return (float)log1p((double)x); }

// XLA ErfInv f32 (Giles polynomial) — exact op order, no FMA contraction
__device__ float erfinv32(float x) {
#pragma clang fp contract(off)
  float nxx = -(x * x);
  float w = -f32_log1p(nxx);
  float p;
  if (w < 5.0f) {
    w = w - 2.5f;
    p = 2.81022636e-08f;
    p = 3.43273939e-07f  + p * w;
    p = -3.5233877e-06f  + p * w;
    p = -4.39150654e-06f + p * w;
    p = 0.00021858087f   + p * w;
    p = -0.00125372503f  + p * w;
    p = -0.00417768164f  + p * w;
    p = 0.246640727f     + p * w;
    p = 1.50140941f      + p * w;
  } else {
    w = sqrtf(w) - 3.0f;
    p = -0.000200214257f;
    p = 0.000100950558f  + p * w;
    p = 0.00134934322f   + p * w;
    p = -0.00367342844f  + p * w;
    p = 0.00573950773f   + p * w;
    p = -0.0076224613f   + p * w;
    p = 0.00943887047f   + p * w;
    p = 1.00167406f      + p * w;
    p = 2.83297682f      + p * w;
  }
  return p * x;
}

__device__ __forceinline__ float normal_from_bits(uint32_t bits) {
#pragma clang fp contract(off)
  float u = unit_from_bits(bits);
  const float LO = -0.99999994f;
  float x = u * 2.0f + LO;
  x = fmaxf(LO, x);
  return 1.4142135623730951f * erfinv32(x);
}

// jax _gamma_one(key, alpha=511.5, log_space=True): returns log(d) + log(V)
__device__ float loggamma_511_5(U2 gkey) {
#pragma clang fp contract(off)
  const float one_third = 1.0f / 3.0f;
  const float d = 511.5f - one_third;
  const float c = one_third / sqrtf(d);   // JAX: one_over_three / lax.sqrt(d)
  U2 key = tf_subkey(gkey, 0u);           // boost subkey unused for alpha>=1
  float V = 1.0f;
  for (int it = 0; it < 64; ++it) {
    U2 knext = tf_subkey(key, 0u);
    U2 xkey  = tf_subkey(key, 1u);
    U2 Ukey  = tf_subkey(key, 2u);
    float x, v;
    U2 xk = xkey;
    do {
      U2 xk_next = tf_subkey(xk, 0u);
      U2 nsub    = tf_subkey(xk, 1u);
      x = normal_from_bits(tf_bits32(nsub, 0u));
      v = 1.0f + x * c;
      xk = xk_next;
    } while (v <= 0.0f);
    float X = x * x;
    V = (v * v) * v;
    float U = unit_from_bits(tf_bits32(Ukey, 0u));
    float sq = 1.0f - 0.0331f * (X * X);
    bool cont;
    if (!(U >= sq)) {
      cont = false;
    } else {
      float logU = f32_log(U);
      float thr = X * 0.5f + d * ((1.0f - V) + f32_log(V));
      cont = (logU >= thr);
    }
    if (!cont) break;
    key = knext;
  }
  return f32_log(d) + f32_log(V);
}

__device__ float beta_elem(U2 k1, uint32_t i) {
#pragma clang fp contract(off)
  U2 ka = tf_subkey(k1, 0u);
  U2 kb = tf_subkey(k1, 1u);
  U2 ga = tf_subkey(ka, i);
  U2 gb = tf_subkey(kb, i);
  float lga = loggamma_511_5(ga);
  float lgb = loggamma_511_5(gb);
  float m  = fmaxf(lga, lgb);
  float ea = f32_exp(lga - m);
  float eb = f32_exp(lgb - m);
  return ea / (ea + eb);
}

// one Wood rejection iteration at chain key K for row i
__device__ __forceinline__ bool wood_try(U2 K, uint32_t i, float& wn) {
#pragma clang fp contract(off)
  const double kappa_d = 80.0, dimr_d = 1023.0;
  const double b_d = dimr_d / (sqrt(4.0 * kappa_d * kappa_d + dimr_d * dimr_d) + 2.0 * kappa_d);
  const double x_d = (1.0 - b_d) / (1.0 + b_d);
  const double c_d = kappa_d * x_d + dimr_d * log(1.0 - x_d * x_d);
  const float bf = (float)b_d, xf = (float)x_d, cf = (float)c_d;
  const float b1p = 1.0f + bf, b1m = 1.0f - bf;

  U2 k1 = tf_subkey(K, 1u);
  U2 k2 = tf_subkey(K, 2u);
  float z = beta_elem(k1, i);
  wn = (1.0f - b1p * z) / (1.0f - b1m * z);
  float u = unit_from_bits(tf_bits32(k2, i));
  float lhs = (80.0f * wn + 1023.0f * f32_log(1.0f - xf * wn)) - cf;
  return lhs >= f32_log(u);
}

// sequential Wood from iteration t_start (chain key K at depth t_start)
__device__ float wood_seq_from(U2 K, uint32_t i, int t_start) {
  float w = 0.0f;
  for (int t = t_start; t < 64; ++t) {
    U2 Kn = tf_subkey(K, 0u);
    float wn;
    if (wood_try(K, i, wn)) { w = wn; break; }
    K = Kn;
  }
  return w;
}

// ---------------------------------------------------------------------------
// Kernel 0: dense streaming convert (int8 table + scales + W fp16), plus
// VALU riders: speculative Wood iters and (chunked path) v_raw normals.
// Block map: [0,64) wood | [64,64+nvr) vr | [.,+128) W | rest embed rows.
// ---------------------------------------------------------------------------
#define NWOODBLK 64
#define NBLK_W   128
#define NBLK_E   ((VOCAB + 3) / 4)    // 12565 (one wave = one vocab row)

__device__ __forceinline__ uint2 cvt4h(float4 a) {
  union { __half h[4]; uint2 u; } pk;
  pk.h[0] = __float2half(a.x); pk.h[1] = __float2half(a.y);
  pk.h[2] = __float2half(a.z); pk.h[3] = __float2half(a.w);
  return pk.u;
}

__device__ __forceinline__ uint32_t quant4(float4 a, float inv) {
  int q0 = __float2int_rn(a.x * inv);
  int q1 = __float2int_rn(a.y * inv);
  int q2 = __float2int_rn(a.z * inv);
  int q3 = __float2int_rn(a.w * inv);
  q0 = max(-127, min(127, q0)); q1 = max(-127, min(127, q1));
  q2 = max(-127, min(127, q2)); q3 = max(-127, min(127, q3));
  return (uint32_t)(uint8_t)q0 | ((uint32_t)(uint8_t)q1 << 8) |
         ((uint32_t)(uint8_t)q2 << 16) | ((uint32_t)(uint8_t)q3 << 24);
}

__global__ __launch_bounds__(256) void convert_kernel(
    const float* __restrict__ embed, const float* __restrict__ W,
    int8_t* __restrict__ embed_i8, float* __restrict__ scales,
    __half* __restrict__ W_h,
    float* __restrict__ spec_w, uint32_t* __restrict__ spec_ok,
    float* __restrict__ vr_buf, int nvr) {
  int b = blockIdx.x;
  int wave = threadIdx.x >> 6, lane = threadIdx.x & 63;
  if (b < NWOODBLK) {
    int g = b * 256 + threadIdx.x;      // 0..16383
    int t = g >> 11;                    // spec iteration 0..7
    int i = g & (NROWS - 1);            // row
    U2 key42; key42.x = 0u; key42.y = 42u;
    U2 K = tf_subkey(key42, 0u);        // kw = K_0
    for (int j = 0; j < t; ++j) K = tf_subkey(K, 0u);
    float wn;
    bool ok = wood_try(K, (uint32_t)i, wn);
    spec_w[t * NROWS + i]  = wn;
    spec_ok[t * NROWS + i] = ok ? 1u : 0u;
  } else if (b < NWOODBLK + nvr) {
    int r = b - NWOODBLK;               // 0..2047
    U2 key42; key42.x = 0u; key42.y = 42u;
    U2 kv = tf_subkey(key42, 1u);
#pragma unroll
    for (int q = 0; q < 4; ++q) {
      int j = threadIdx.x + q * 256;
      vr_buf[(size_t)r * HID + j] =
          normal_from_bits(tf_bits32(kv, (uint32_t)(r * HID + j)));
    }
  } else if (b < NWOODBLK + nvr + NBLK_W) {
    int wid = (b - NWOODBLK - nvr) * 4 + wave;    // 0..511
    size_t base = (size_t)wid * 128 + lane;
    const float4* src = (const float4*)W;
    uint2* dst = (uint2*)W_h;
    float4 a = src[base];
    float4 c = src[base + 64];
    dst[base]      = cvt4h(a);
    dst[base + 64] = cvt4h(c);
  } else {
    int wid = (b - NWOODBLK - nvr - NBLK_W) * 4 + wave; // vocab row
    if (wid < VOCAB) {
      size_t base = (size_t)wid * 128 + lane;     // float4 index
      const float4* src = (const float4*)embed;
      float4 a = src[base];
      float4 c = src[base + 64];
      float m = fmaxf(fmaxf(fmaxf(fabsf(a.x), fabsf(a.y)), fmaxf(fabsf(a.z), fabsf(a.w))),
                      fmaxf(fmaxf(fabsf(c.x), fabsf(c.y)), fmaxf(fabsf(c.z), fabsf(c.w))));
#pragma unroll
      for (int off = 1; off < 64; off <<= 1) m = fmaxf(m, __shfl_xor(m, off, 64));
      float inv   = (m > 0.0f) ? 127.0f / m : 0.0f;
      float scale = (m > 0.0f) ? m / 127.0f : 0.0f;
      uint32_t* dst = (uint32_t*)embed_i8;
      size_t b32 = (size_t)wid * 128 + lane;      // uint32 index (4 bytes each)
      dst[b32]      = quant4(a, inv);
      dst[b32 + 64] = quant4(c, inv);
      if (lane == 0) scales[wid] = scale;
    }
  }
}

// ---------------------------------------------------------------------------
// Kernel 1a (chunked): vocab-chunked int8 gather -> fp16 partial sums.
// chunk = bid & 7 rides the round-robin block->XCD map so each XCD streams a
// 3.2 MB L2-resident table slice. Wave-uniform token filter (~16 hits/128).
// ---------------------------------------------------------------------------
__global__ __launch_bounds__(256) void gather_chunk_kernel(
    const int* __restrict__ add_tok, const int* __restrict__ rem_tok,
    const int8_t* __restrict__ embed_i8, const float* __restrict__ scales,
    __half* __restrict__ partial) {
  int bid = blockIdx.x;
  int chunk = bid & (NCHUNK - 1);
  int rp = bid >> 3;
  int wave = threadIdx.x >> 6, lane = threadIdx.x & 63;
  int row = rp * 2 + (wave & 1);
  int which = wave >> 1;
  const int lo = (chunk * VOCAB) / NCHUNK;
  const int hi = ((chunk + 1) * VOCAB) / NCHUNK;
  const int* tok = (which == 0 ? add_tok : rem_tok) + (size_t)row * SEQ;
  int c = lane * 8;
  float acc[8] = {};
  for (int s = 0; s < SEQ; ++s) {
    int t = tok[s];                      // wave-uniform
    if (t >= lo && t < hi) {
      float sc = scales[t];
      uint2 v = *(const uint2*)&embed_i8[(size_t)t * EMB + c];
      const int8_t* bb = (const int8_t*)&v;
#pragma unroll
      for (int j = 0; j < 8; ++j) acc[j] += sc * (float)bb[j];
    }
  }
  union { __half h[8]; uint4 u; } pk;
#pragma unroll
  for (int j = 0; j < 8; ++j) pk.h[j] = __float2half(acc[j]);
  *(uint4*)&partial[(((size_t)chunk * 2 + which) * NROWS + row) * EMB + c] = pk.u;
}

// ---------------------------------------------------------------------------
// Kernel 1b: reduce 8 fp16 partials -> fp16 sums (f32 accumulate).
// ---------------------------------------------------------------------------
__global__ __launch_bounds__(256) void reduce_partial_kernel(
    const __half* __restrict__ partial, __half* __restrict__ sums_h) {
  const int NG = 2 * NROWS * EMB / 8;    // 262144 uint4 groups
  int g = blockIdx.x * 256 + threadIdx.x;
  if (g >= NG) return;
  float acc[8] = {};
  const uint4* src = (const uint4*)partial;
#pragma unroll
  for (int ch = 0; ch < NCHUNK; ++ch) {
    uint4 v = src[(size_t)ch * NG + g];
    const __half* h = (const __half*)&v;
#pragma unroll
    for (int j = 0; j < 8; ++j) acc[j] += __half2float(h[j]);
  }
  union { __half h[8]; uint4 u; } pk;
#pragma unroll
  for (int j = 0; j < 8; ++j) pk.h[j] = __float2half(acc[j]);
  ((uint4*)sums_h)[g] = pk.u;
}

// ---------------------------------------------------------------------------
// Kernel 1c (round-13 path): monolithic int8 gather + vr riders.
// ---------------------------------------------------------------------------
__global__ __launch_bounds__(256) void gather_vr_kernel(
    const int* __restrict__ add_tok, const int* __restrict__ rem_tok,
    const int8_t* __restrict__ embed_i8, const float* __restrict__ scales,
    __half* __restrict__ sums_h, float* __restrict__ vr_buf) {
  int b = blockIdx.x;
  if (b < NROWS / 2) {
    int rb = b * 2;
    int wave = threadIdx.x >> 6;
    int lane = threadIdx.x & 63;
    int row = rb + (wave & 1);
    int which = wave >> 1;
    const int* tok = (which == 0 ? add_tok : rem_tok) + (size_t)row * SEQ;
    int c = lane * 8;
    float acc[8] = {};
    for (int s = 0; s < SEQ; s += 2) {
      int t0 = tok[s], t1 = tok[s + 1];
      float s0 = scales[t0], s1 = scales[t1];
      uint2 v0 = *(const uint2*)&embed_i8[(size_t)t0 * EMB + c];
      uint2 v1 = *(const uint2*)&embed_i8[(size_t)t1 * EMB + c];
      const int8_t* b0 = (const int8_t*)&v0;
      const int8_t* b1 = (const int8_t*)&v1;
#pragma unroll
      for (int j = 0; j < 8; ++j) acc[j] += s0 * (float)b0[j];
#pragma unroll
      for (int j = 0; j < 8; ++j) acc[j] += s1 * (float)b1[j];
    }
    union { __half h[8]; uint4 u; } pk;
#pragma unroll
    for (int j = 0; j < 8; ++j) pk.h[j] = __float2half(acc[j]);
    *(uint4*)&sums_h[((size_t)which * NROWS + row) * EMB + c] = pk.u;
  } else {
    int r = b - NROWS / 2;
    U2 key42; key42.x = 0u; key42.y = 42u;
    U2 kv = tf_subkey(key42, 1u);
#pragma unroll
    for (int q = 0; q < 4; ++q) {
      int j = threadIdx.x + q * 256;
      vr_buf[(size_t)r * HID + j] =
          normal_from_bits(tf_bits32(kv, (uint32_t)(r * HID + j)));
    }
  }
}

// ---------------------------------------------------------------------------
// Kernel 2: MFMA f16 GEMM. combined[r][c] = dot(sums[c-half][r], W[c&511]).
// ---------------------------------------------------------------------------
__global__ __launch_bounds__(256) void gemm_mfma_kernel(
    const __half* __restrict__ sums_h, const __half* __restrict__ W_h,
    float* __restrict__ out) {
  int wave = threadIdx.x >> 6, lane = threadIdx.x & 63;
  int r0 = blockIdx.x * 16;
  int c0 = blockIdx.y * 256 + wave * 64;
  const __half* A = sums_h + ((c0 < 512) ? 0 : (size_t)NROWS * EMB);
  int wc0 = c0 & 511;
  int l15 = lane & 15, kg = lane >> 4;
  const _Float16* arow = (const _Float16*)&A[(size_t)(r0 + l15) * EMB];
  const _Float16* b0p  = (const _Float16*)&W_h[(size_t)(wc0 +  0 + l15) * EMB];
  const _Float16* b1p  = (const _Float16*)&W_h[(size_t)(wc0 + 16 + l15) * EMB];
  const _Float16* b2p  = (const _Float16*)&W_h[(size_t)(wc0 + 32 + l15) * EMB];
  const _Float16* b3p  = (const _Float16*)&W_h[(size_t)(wc0 + 48 + l15) * EMB];
  f32x4 acc0 = {0.f,0.f,0.f,0.f}, acc1 = acc0, acc2 = acc0, acc3 = acc0;
  for (int k0 = 0; k0 < EMB; k0 += 16) {
    int k = k0 + 4 * kg;
    f16x4 af = *(const f16x4*)&arow[k];
    f16x4 b0 = *(const f16x4*)&b0p[k];
    f16x4 b1 = *(const f16x4*)&b1p[k];
    f16x4 b2 = *(const f16x4*)&b2p[k];
    f16x4 b3 = *(const f16x4*)&b3p[k];
    acc0 = __builtin_amdgcn_mfma_f32_16x16x16f16(af, b0, acc0, 0, 0, 0);
    acc1 = __builtin_amdgcn_mfma_f32_16x16x16f16(af, b1, acc1, 0, 0, 0);
    acc2 = __builtin_amdgcn_mfma_f32_16x16x16f16(af, b2, acc2, 0, 0, 0);
    acc3 = __builtin_amdgcn_mfma_f32_16x16x16f16(af, b3, acc3, 0, 0, 0);
  }
#pragma unroll
  for (int i = 0; i < 4; ++i) {
    size_t rr = (size_t)(r0 + 4 * kg + i) * HID + c0 + l15;
    out[rr +  0] = acc0[i];
    out[rr + 16] = acc1[i];
    out[rr + 32] = acc2[i];
    out[rr + 48] = acc3[i];
  }
}

// ---------------------------------------------------------------------------
// Kernel 3: per-row finalize — mu from d_out, vr from ws, w from spec arrays.
// ---------------------------------------------------------------------------
__device__ __forceinline__ float block_reduce_sum256(float v, float* red) {
#pragma unroll
  for (int off = 32; off > 0; off >>= 1) v += __shfl_down(v, off, 64);
  if ((threadIdx.x & 63) == 0) red[threadIdx.x >> 6] = v;
  __syncthreads();
  float s = red[0] + red[1] + red[2] + red[3];
  __syncthreads();
  return s;
}

__global__ __launch_bounds__(256) void finalize_kernel(
    const float* __restrict__ spec_w, const uint32_t* __restrict__ spec_ok,
    const float* __restrict__ vr_buf, float* __restrict__ out) {
#pragma clang fp contract(off)
  __shared__ float red[4];
  int r = blockIdx.x, tid = threadIdx.x;
  U2 key42; key42.x = 0u; key42.y = 42u;
  U2 kt = tf_subkey(key42, 2u);

  float mu[4], vr[4];
#pragma unroll
  for (int q = 0; q < 4; ++q) {
    int j = tid + q * 256;
    mu[q] = out[(size_t)r * HID + j];
    vr[q] = vr_buf[(size_t)r * HID + j];
  }

  float w = 0.0f;
  int found = -1;
#pragma unroll
  for (int t = 0; t < NSPEC; ++t) {
    if (found < 0 && spec_ok[t * NROWS + r]) { w = spec_w[t * NROWS + r]; found = t; }
  }
  if (found < 0) {
    U2 K = tf_subkey(key42, 0u);
    for (int j = 0; j < NSPEC; ++j) K = tf_subkey(K, 0u);
    w = wood_seq_from(K, (uint32_t)r, NSPEC);
  }
  float trand = unit_from_bits(tf_bits32(kt, (uint32_t)r)) * 0.1f;

  float ss = mu[0]*mu[0] + mu[1]*mu[1] + mu[2]*mu[2] + mu[3]*mu[3];
  ss = block_reduce_sum256(ss, red);
  float munorm = sqrtf(ss);
  float safe = fmaxf(munorm, 1e-20f);
  float muh[4];
#pragma unroll
  for (int q = 0; q < 4; ++q) muh[q] = mu[q] / safe;
  float pp = muh[0]*vr[0] + muh[1]*vr[1] + muh[2]*vr[2] + muh[3]*vr[3];
  pp = block_reduce_sum256(pp, red);
  float ortho[4];
#pragma unroll
  for (int q = 0; q < 4; ++q) ortho[q] = vr[q] - muh[q] * pp;
  float os = ortho[0]*ortho[0] + ortho[1]*ortho[1] + ortho[2]*ortho[2] + ortho[3]*ortho[3];
  os = block_reduce_sum256(os, red);
  float on = sqrtf(os);

  float sqw = sqrtf(1.0f - w * w);
  float munoise = fminf(fmaxf(munorm, 0.0f), 13.9f) + trand;
#pragma unroll
  for (int q = 0; q < 4; ++q) {
    int j = tid + q * 256;
    float v = ortho[q] / on;
    out[(size_t)r * HID + j] = (v * sqw + muh[q] * w) * munoise;
  }
}

// ---------------------------------------------------------------------------
// Fallback path kernels (f32, round-5 behavior) — used only if ws too small
// ---------------------------------------------------------------------------
__global__ __launch_bounds__(128) void gather_sum_kernel(
    const int* __restrict__ add_tok, const int* __restrict__ rem_tok,
    const float* __restrict__ embed, float* __restrict__ sums) {
  int rb = blockIdx.x * GR;
  int which = blockIdx.y;
  const int* tok = (which == 0 ? add_tok : rem_tok);
  __shared__ int t[GR][SEQ];
  for (int q = threadIdx.x; q < GR * SEQ; q += 128) {
    int rr = q >> 7, ss = q & 127;
    t[rr][ss] = tok[(size_t)(rb + rr) * SEQ + ss];
  }
  __syncthreads();
  int c = threadIdx.x * 4;
  float4 a0 = make_float4(0.f,0.f,0.f,0.f), a1 = a0, a2 = a0, a3 = a0;
  for (int s = 0; s < SEQ; ++s) {
    float4 v0 = *(const float4*)&embed[(size_t)t[0][s] * EMB + c];
    float4 v1 = *(const float4*)&embed[(size_t)t[1][s] * EMB + c];
    float4 v2 = *(const float4*)&embed[(size_t)t[2][s] * EMB + c];
    float4 v3 = *(const float4*)&embed[(size_t)t[3][s] * EMB + c];
    a0.x += v0.x; a0.y += v0.y; a0.z += v0.z; a0.w += v0.w;
    a1.x += v1.x; a1.y += v1.y; a1.z += v1.z; a1.w += v1.w;
    a2.x += v2.x; a2.y += v2.y; a2.z += v2.z; a2.w += v2.w;
    a3.x += v3.x; a3.y += v3.y; a3.z += v3.z; a3.w += v3.w;
  }
  size_t base = ((size_t)which * NROWS + rb) * EMB + c;
  *(float4*)&sums[base + 0 * EMB] = a0;
  *(float4*)&sums[base + 1 * EMB] = a1;
  *(float4*)&sums[base + 2 * EMB] = a2;
  *(float4*)&sums[base + 3 * EMB] = a3;
}

__global__ __launch_bounds__(256) void gemm_kernel(
    const float* __restrict__ sums, const float* __restrict__ W,
    float* __restrict__ out) {
  __shared__ float As[16][64];
  __shared__ float Bs[16][64];
  int r0 = blockIdx.x * 64;
  int c0 = blockIdx.y * 64;
  const float* A = sums + ((c0 < 512) ? 0 : (size_t)NROWS * EMB);
  int wc0 = c0 & 511;
  int tid = threadIdx.x;
  int tx = tid & 15, ty = tid >> 4;
  int lr = tid >> 2, lk = (tid & 3) * 4;
  float acc[4][4] = {};
  for (int k0 = 0; k0 < EMB; k0 += 16) {
    float4 av = *(const float4*)&A[(size_t)(r0 + lr) * EMB + k0 + lk];
    float4 bv = *(const float4*)&W[(size_t)(wc0 + lr) * EMB + k0 + lk];
    __syncthreads();
    As[lk + 0][lr] = av.x; As[lk + 1][lr] = av.y; As[lk + 2][lr] = av.z; As[lk + 3][lr] = av.w;
    Bs[lk + 0][lr] = bv.x; Bs[lk + 1][lr] = bv.y; Bs[lk + 2][lr] = bv.z; Bs[lk + 3][lr] = bv.w;
    __syncthreads();
#pragma unroll
    for (int kk = 0; kk < 16; ++kk) {
      float a[4], b[4];
#pragma unroll
      for (int m = 0; m < 4; ++m) a[m] = As[kk][ty * 4 + m];
#pragma unroll
      for (int n = 0; n < 4; ++n) b[n] = Bs[kk][tx * 4 + n];
#pragma unroll
      for (int m = 0; m < 4; ++m)
#pragma unroll
        for (int n = 0; n < 4; ++n) acc[m][n] += a[m] * b[n];
    }
  }
#pragma unroll
  for (int m = 0; m < 4; ++m)
#pragma unroll
    for (int n = 0; n < 4; ++n)
      out[(size_t)(r0 + ty * 4 + m) * HID + c0 + tx * 4 + n] = acc[m][n];
}

// fallback finalize with inline sequential wood + inline normals
__global__ __launch_bounds__(256) void finalize_inline_kernel(float* __restrict__ out) {
#pragma clang fp contract(off)
  __shared__ float red[4];
  int r = blockIdx.x, tid = threadIdx.x;
  U2 key42; key42.x = 0u; key42.y = 42u;
  U2 kv = tf_subkey(key42, 1u);
  U2 kt = tf_subkey(key42, 2u);

  float mu[4], vr[4];
#pragma unroll
  for (int q = 0; q < 4; ++q) {
    int j = tid + q * 256;
    mu[q] = out[(size_t)r * HID + j];
    vr[q] = normal_from_bits(tf_bits32(kv, (uint32_t)(r * HID + j)));
  }
  U2 kw = tf_subkey(key42, 0u);
  float w = wood_seq_from(kw, (uint32_t)r, 0);
  float trand = unit_from_bits(tf_bits32(kt, (uint32_t)r)) * 0.1f;

  float ss = mu[0]*mu[0] + mu[1]*mu[1] + mu[2]*mu[2] + mu[3]*mu[3];
  ss = block_reduce_sum256(ss, red);
  float munorm = sqrtf(ss);
  float safe = fmaxf(munorm, 1e-20f);
  float muh[4];
#pragma unroll
  for (int q = 0; q < 4; ++q) muh[q] = mu[q] / safe;
  float pp = muh[0]*vr[0] + muh[1]*vr[1] + muh[2]*vr[2] + muh[3]*vr[3];
  pp = block_reduce_sum256(pp, red);
  float ortho[4];
#pragma unroll
  for (int q = 0; q < 4; ++q) ortho[q] = vr[q] - muh[q] * pp;
  float os = ortho[0]*ortho[0] + ortho[1]*ortho[1] + ortho[2]*ortho[2] + ortho[3]*ortho[3];
  os = block_reduce_sum256(os, red);
  float on = sqrtf(os);

  float sqw = sqrtf(1.0f - w * w);
  float munoise = fminf(fmaxf(munorm, 0.0f), 13.9f) + trand;
#pragma unroll
  for (int q = 0; q < 4; ++q) {
    int j = tid + q * 256;
    float v = ortho[q] / on;
    out[(size_t)r * HID + j] = (v * sqw + muh[q] * w) * munoise;
  }
}

// ---------------------------------------------------------------------------
extern "C" void kernel_launch(void* const* d_in, const int* in_sizes, int n_in,
                              void* d_out, int out_size, void* d_ws, size_t ws_size,
                              hipStream_t stream) {
  const int*   add_tok = (const int*)d_in[0];
  const int*   rem_tok = (const int*)d_in[1];
  const float* embed   = (const float*)d_in[2];
  const float* W       = (const float*)d_in[3];
  float* out = (float*)d_out;

  const size_t EMBED_I8_BYTES = (size_t)VOCAB * EMB;                      // 25,731,584
  const size_t SCALE_BYTES    = (size_t)((VOCAB + 63) & ~63) * 4;         //    201,280
  const size_t W_H_BYTES      = (size_t)512 * EMB * sizeof(__half);       //    524,288
  const size_t SUMS_H_BYTES   = (size_t)2 * NROWS * EMB * sizeof(__half); //  4,194,304
  const size_t SPEC_BYTES     = (size_t)NSPEC * NROWS * 4;                //     65,536
  const size_t VR_BYTES       = (size_t)NROWS * HID * sizeof(float);      //  8,388,608
  const size_t PART_BYTES     = (size_t)NCHUNK * 2 * NROWS * EMB * 2;     // 33,554,432
  const size_t NEED_R13   = EMBED_I8_BYTES + SCALE_BYTES + W_H_BYTES + SUMS_H_BYTES
                          + 2 * SPEC_BYTES + VR_BYTES;                    // ~39.1 MB
  const size_t NEED_CHUNK = NEED_R13 + PART_BYTES;                        // ~72.7 MB

  if (ws_size >= NEED_R13) {
    char* p = (char*)d_ws;
    int8_t*   embed_i8 = (int8_t*)p;   p += EMBED_I8_BYTES;
    float*    scales   = (float*)p;    p += SCALE_BYTES;
    __half*   W_h      = (__half*)p;   p += W_H_BYTES;
    __half*   sums_h   = (__half*)p;   p += SUMS_H_BYTES;
    float*    spec_w   = (float*)p;    p += SPEC_BYTES;
    uint32_t* spec_ok  = (uint32_t*)p; p += SPEC_BYTES;
    float*    vr_buf   = (float*)p;    p += VR_BYTES;

    if (ws_size >= NEED_CHUNK) {
      __half* partial = (__half*)p;
      convert_kernel<<<NWOODBLK + NROWS + NBLK_W + NBLK_E, 256, 0, stream>>>(
          embed, W, embed_i8, scales, W_h, spec_w, spec_ok, vr_buf, NROWS);
      gather_chunk_kernel<<<(NROWS / 2) * NCHUNK, 256, 0, stream>>>(
          add_tok, rem_tok, embed_i8, scales, partial);
      reduce_partial_kernel<<<(2 * NROWS * EMB / 8 + 255) / 256, 256, 0, stream>>>(
          partial, sums_h);
    } else {
      convert_kernel<<<NWOODBLK + NBLK_W + NBLK_E, 256, 0, stream>>>(
          embed, W, embed_i8, scales, W_h, spec_w, spec_ok, vr_buf, 0);
      gather_vr_kernel<<<NROWS / 2 + NROWS, 256, 0, stream>>>(
          add_tok, rem_tok, embed_i8, scales, sums_h, vr_buf);
    }
    gemm_mfma_kernel<<<dim3(NROWS / 16, HID / 256), 256, 0, stream>>>(sums_h, W_h, out);
    finalize_kernel<<<NROWS, 256, 0, stream>>>(spec_w, spec_ok, vr_buf, out);
  } else {
    float* sums = (float*)d_ws;
    gather_sum_kernel<<<dim3(NROWS / GR, 2), 128, 0, stream>>>(add_tok, rem_tok, embed, sums);
    gemm_kernel<<<dim3(NROWS / 64, HID / 64), 256, 0, stream>>>(sums, W, out);
    finalize_inline_kernel<<<NROWS, 256, 0, stream>>>(out);
  }
}

// Round 15
// 125.230 us; speedup vs baseline: 1.8417x; 1.8417x over previous
//
#include <hip/hip_runtime.h>
#include <hip/hip_fp16.h>
#include <stdint.h>
#include <math.h>

// Problem constants
#define NROWS 2048
#define SEQ   128
#define EMB   512
#define HID   1024
#define VOCAB 50257
#define GR    4      // fallback gather: rows per block
#define NSPEC 8      // speculative Wood iterations
#define NCHUNK 8     // vocab chunks (one per XCD)

typedef _Float16 f16x4 __attribute__((ext_vector_type(4)));
typedef float    f32x4 __attribute__((ext_vector_type(4)));

// ---------------------------------------------------------------------------
// threefry2x32 (JAX PRNG), exact
// ---------------------------------------------------------------------------
struct U2 { uint32_t x, y; };

__device__ __forceinline__ uint32_t rotl32(uint32_t v, int r) {
  return (v << r) | (v >> (32 - r));
}

__device__ __forceinline__ U2 tf2x32(U2 key, uint32_t x0, uint32_t x1) {
  uint32_t ks0 = key.x, ks1 = key.y;
  uint32_t ks2 = ks0 ^ ks1 ^ 0x1BD11BDAu;
  x0 += ks0; x1 += ks1;
  x0 += x1; x1 = rotl32(x1, 13); x1 ^= x0;
  x0 += x1; x1 = rotl32(x1, 15); x1 ^= x0;
  x0 += x1; x1 = rotl32(x1, 26); x1 ^= x0;
  x0 += x1; x1 = rotl32(x1, 6);  x1 ^= x0;
  x0 += ks1; x1 += ks2 + 1u;
  x0 += x1; x1 = rotl32(x1, 17); x1 ^= x0;
  x0 += x1; x1 = rotl32(x1, 29); x1 ^= x0;
  x0 += x1; x1 = rotl32(x1, 16); x1 ^= x0;
  x0 += x1; x1 = rotl32(x1, 24); x1 ^= x0;
  x0 += ks2; x1 += ks0 + 2u;
  x0 += x1; x1 = rotl32(x1, 13); x1 ^= x0;
  x0 += x1; x1 = rotl32(x1, 15); x1 ^= x0;
  x0 += x1; x1 = rotl32(x1, 26); x1 ^= x0;
  x0 += x1; x1 = rotl32(x1, 6);  x1 ^= x0;
  x0 += ks0; x1 += ks1 + 3u;
  x0 += x1; x1 = rotl32(x1, 17); x1 ^= x0;
  x0 += x1; x1 = rotl32(x1, 29); x1 ^= x0;
  x0 += x1; x1 = rotl32(x1, 16); x1 ^= x0;
  x0 += x1; x1 = rotl32(x1, 24); x1 ^= x0;
  x0 += ks1; x1 += ks2 + 4u;
  x0 += x1; x1 = rotl32(x1, 13); x1 ^= x0;
  x0 += x1; x1 = rotl32(x1, 15); x1 ^= x0;
  x0 += x1; x1 = rotl32(x1, 26); x1 ^= x0;
  x0 += x1; x1 = rotl32(x1, 6);  x1 ^= x0;
  x0 += ks2; x1 += ks0 + 5u;
  U2 r; r.x = x0; r.y = x1; return r;
}

__device__ __forceinline__ U2 tf_subkey(U2 key, uint32_t i) { return tf2x32(key, 0u, i); }
__device__ __forceinline__ uint32_t tf_bits32(U2 key, uint32_t idx) {
  U2 r = tf2x32(key, 0u, idx);
  return r.x ^ r.y;
}

__device__ __forceinline__ float unit_from_bits(uint32_t b) {
  uint32_t fb = (b >> 9) | 0x3f800000u;
  return __uint_as_float(fb) - 1.0f;
}

__device__ __forceinline__ float f32_log(float x)  { return (float)log((double)x); }
__device__ __forceinline__ float f32_exp(float x)  { return (float)exp((double)x); }
__device__ __forceinline__ float f32_log1p(float x){ return (float)log1p((double)x); }

// XLA ErfInv f32 (Giles polynomial) — exact op order, no FMA contraction
__device__ float erfinv32(float x) {
#pragma clang fp contract(off)
  float nxx = -(x * x);
  float w = -f32_log1p(nxx);
  float p;
  if (w < 5.0f) {
    w = w - 2.5f;
    p = 2.81022636e-08f;
    p = 3.43273939e-07f  + p * w;
    p = -3.5233877e-06f  + p * w;
    p = -4.39150654e-06f + p * w;
    p = 0.00021858087f   + p * w;
    p = -0.00125372503f  + p * w;
    p = -0.00417768164f  + p * w;
    p = 0.246640727f     + p * w;
    p = 1.50140941f      + p * w;
  } else {
    w = sqrtf(w) - 3.0f;
    p = -0.000200214257f;
    p = 0.000100950558f  + p * w;
    p = 0.00134934322f   + p * w;
    p = -0.00367342844f  + p * w;
    p = 0.00573950773f   + p * w;
    p = -0.0076224613f   + p * w;
    p = 0.00943887047f   + p * w;
    p = 1.00167406f      + p * w;
    p = 2.83297682f      + p * w;
  }
  return p * x;
}

__device__ __forceinline__ float normal_from_bits(uint32_t bits) {
#pragma clang fp contract(off)
  float u = unit_from_bits(bits);
  const float LO = -0.99999994f;
  float x = u * 2.0f + LO;
  x = fmaxf(LO, x);
  return 1.4142135623730951f * erfinv32(x);
}

// jax _gamma_one(key, alpha=511.5, log_space=True): returns log(d) + log(V)
__device__ float loggamma_511_5(U2 gkey) {
#pragma clang fp contract(off)
  const float one_third = 1.0f / 3.0f;
  const float d = 511.5f - one_third;
  const float c = one_third / sqrtf(d);   // JAX: one_over_three / lax.sqrt(d)
  U2 key = tf_subkey(gkey, 0u);           // boost subkey unused for alpha>=1
  float V = 1.0f;
  for (int it = 0; it < 64; ++it) {
    U2 knext = tf_subkey(key, 0u);
    U2 xkey  = tf_subkey(key, 1u);
    U2 Ukey  = tf_subkey(key, 2u);
    float x, v;
    U2 xk = xkey;
    do {
      U2 xk_next = tf_subkey(xk, 0u);
      U2 nsub    = tf_subkey(xk, 1u);
      x = normal_from_bits(tf_bits32(nsub, 0u));
      v = 1.0f + x * c;
      xk = xk_next;
    } while (v <= 0.0f);
    float X = x * x;
    V = (v * v) * v;
    float U = unit_from_bits(tf_bits32(Ukey, 0u));
    float sq = 1.0f - 0.0331f * (X * X);
    bool cont;
    if (!(U >= sq)) {
      cont = false;
    } else {
      float logU = f32_log(U);
      float thr = X * 0.5f + d * ((1.0f - V) + f32_log(V));
      cont = (logU >= thr);
    }
    if (!cont) break;
    key = knext;
  }
  return f32_log(d) + f32_log(V);
}

__device__ float beta_elem(U2 k1, uint32_t i) {
#pragma clang fp contract(off)
  U2 ka = tf_subkey(k1, 0u);
  U2 kb = tf_subkey(k1, 1u);
  U2 ga = tf_subkey(ka, i);
  U2 gb = tf_subkey(kb, i);
  float lga = loggamma_511_5(ga);
  float lgb = loggamma_511_5(gb);
  float m  = fmaxf(lga, lgb);
  float ea = f32_exp(lga - m);
  float eb = f32_exp(lgb - m);
  return ea / (ea + eb);
}

// one Wood rejection iteration at chain key K for row i
__device__ __forceinline__ bool wood_try(U2 K, uint32_t i, float& wn) {
#pragma clang fp contract(off)
  const double kappa_d = 80.0, dimr_d = 1023.0;
  const double b_d = dimr_d / (sqrt(4.0 * kappa_d * kappa_d + dimr_d * dimr_d) + 2.0 * kappa_d);
  const double x_d = (1.0 - b_d) / (1.0 + b_d);
  const double c_d = kappa_d * x_d + dimr_d * log(1.0 - x_d * x_d);
  const float bf = (float)b_d, xf = (float)x_d, cf = (float)c_d;
  const float b1p = 1.0f + bf, b1m = 1.0f - bf;

  U2 k1 = tf_subkey(K, 1u);
  U2 k2 = tf_subkey(K, 2u);
  float z = beta_elem(k1, i);
  wn = (1.0f - b1p * z) / (1.0f - b1m * z);
  float u = unit_from_bits(tf_bits32(k2, i));
  float lhs = (80.0f * wn + 1023.0f * f32_log(1.0f - xf * wn)) - cf;
  return lhs >= f32_log(u);
}

// sequential Wood from iteration t_start (chain key K at depth t_start)
__device__ float wood_seq_from(U2 K, uint32_t i, int t_start) {
  float w = 0.0f;
  for (int t = t_start; t < 64; ++t) {
    U2 Kn = tf_subkey(K, 0u);
    float wn;
    if (wood_try(K, i, wn)) { w = wn; break; }
    K = Kn;
  }
  return w;
}

// ---------------------------------------------------------------------------
// Kernel 0: dense streaming convert (int8 table + scales + W fp16), plus
// VALU riders: speculative Wood iters and (chunked path) v_raw normals.
// ---------------------------------------------------------------------------
#define NWOODBLK 64
#define NBLK_W   128
#define NBLK_E   ((VOCAB + 3) / 4)    // 12565 (one wave = one vocab row)

__device__ __forceinline__ uint2 cvt4h(float4 a) {
  union { __half h[4]; uint2 u; } pk;
  pk.h[0] = __float2half(a.x); pk.h[1] = __float2half(a.y);
  pk.h[2] = __float2half(a.z); pk.h[3] = __float2half(a.w);
  return pk.u;
}

__device__ __forceinline__ uint32_t quant4(float4 a, float inv) {
  int q0 = __float2int_rn(a.x * inv);
  int q1 = __float2int_rn(a.y * inv);
  int q2 = __float2int_rn(a.z * inv);
  int q3 = __float2int_rn(a.w * inv);
  q0 = max(-127, min(127, q0)); q1 = max(-127, min(127, q1));
  q2 = max(-127, min(127, q2)); q3 = max(-127, min(127, q3));
  return (uint32_t)(uint8_t)q0 | ((uint32_t)(uint8_t)q1 << 8) |
         ((uint32_t)(uint8_t)q2 << 16) | ((uint32_t)(uint8_t)q3 << 24);
}

__global__ __launch_bounds__(256) void convert_kernel(
    const float* __restrict__ embed, const float* __restrict__ W,
    int8_t* __restrict__ embed_i8, float* __restrict__ scales,
    __half* __restrict__ W_h,
    float* __restrict__ spec_w, uint32_t* __restrict__ spec_ok,
    float* __restrict__ vr_buf, int nvr) {
  int b = blockIdx.x;
  int wave = threadIdx.x >> 6, lane = threadIdx.x & 63;
  if (b < NWOODBLK) {
    int g = b * 256 + threadIdx.x;      // 0..16383
    int t = g >> 11;                    // spec iteration 0..7
    int i = g & (NROWS - 1);            // row
    U2 key42; key42.x = 0u; key42.y = 42u;
    U2 K = tf_subkey(key42, 0u);        // kw = K_0
    for (int j = 0; j < t; ++j) K = tf_subkey(K, 0u);
    float wn;
    bool ok = wood_try(K, (uint32_t)i, wn);
    spec_w[t * NROWS + i]  = wn;
    spec_ok[t * NROWS + i] = ok ? 1u : 0u;
  } else if (b < NWOODBLK + nvr) {
    int r = b - NWOODBLK;               // 0..2047
    U2 key42; key42.x = 0u; key42.y = 42u;
    U2 kv = tf_subkey(key42, 1u);
#pragma unroll
    for (int q = 0; q < 4; ++q) {
      int j = threadIdx.x + q * 256;
      vr_buf[(size_t)r * HID + j] =
          normal_from_bits(tf_bits32(kv, (uint32_t)(r * HID + j)));
    }
  } else if (b < NWOODBLK + nvr + NBLK_W) {
    int wid = (b - NWOODBLK - nvr) * 4 + wave;    // 0..511
    size_t base = (size_t)wid * 128 + lane;
    const float4* src = (const float4*)W;
    uint2* dst = (uint2*)W_h;
    float4 a = src[base];
    float4 c = src[base + 64];
    dst[base]      = cvt4h(a);
    dst[base + 64] = cvt4h(c);
  } else {
    int wid = (b - NWOODBLK - nvr - NBLK_W) * 4 + wave; // vocab row
    if (wid < VOCAB) {
      size_t base = (size_t)wid * 128 + lane;     // float4 index
      const float4* src = (const float4*)embed;
      float4 a = src[base];
      float4 c = src[base + 64];
      float m = fmaxf(fmaxf(fmaxf(fabsf(a.x), fabsf(a.y)), fmaxf(fabsf(a.z), fabsf(a.w))),
                      fmaxf(fmaxf(fabsf(c.x), fabsf(c.y)), fmaxf(fabsf(c.z), fabsf(c.w))));
#pragma unroll
      for (int off = 1; off < 64; off <<= 1) m = fmaxf(m, __shfl_xor(m, off, 64));
      float inv   = (m > 0.0f) ? 127.0f / m : 0.0f;
      float scale = (m > 0.0f) ? m / 127.0f : 0.0f;
      uint32_t* dst = (uint32_t*)embed_i8;
      size_t b32 = (size_t)wid * 128 + lane;      // uint32 index (4 bytes each)
      dst[b32]      = quant4(a, inv);
      dst[b32 + 64] = quant4(c, inv);
      if (lane == 0) scales[wid] = scale;
    }
  }
}

// ---------------------------------------------------------------------------
// Kernel 1a (chunked v2): ballot-compacted vocab-chunked gather.
// Wave loads its 128 tokens ONCE, ballots the in-chunk mask, iterates only
// set bits (~16) with shfl token broadcast. chunk = bid&7 keeps each XCD's
// 3.2 MB table slice L2-resident (validated round 14: FETCH 135->32 MB).
// ---------------------------------------------------------------------------
__global__ __launch_bounds__(256) void gather_chunk_kernel(
    const int* __restrict__ add_tok, const int* __restrict__ rem_tok,
    const int8_t* __restrict__ embed_i8, const float* __restrict__ scales,
    __half* __restrict__ partial) {
  int bid = blockIdx.x;
  int chunk = bid & (NCHUNK - 1);
  int rp = bid >> 3;
  int wave = threadIdx.x >> 6, lane = threadIdx.x & 63;
  int row = rp * 2 + (wave & 1);
  int which = wave >> 1;
  const int lo = (chunk * VOCAB) / NCHUNK;
  const int hi = ((chunk + 1) * VOCAB) / NCHUNK;
  const int* tok = (which == 0 ? add_tok : rem_tok) + (size_t)row * SEQ;
  int c = lane * 8;

  int t0 = tok[lane];
  int t1 = tok[lane + 64];
  unsigned long long m0 = __ballot(t0 >= lo && t0 < hi);
  unsigned long long m1 = __ballot(t1 >= lo && t1 < hi);

  float acc[8] = {};
  while (m0) {
    int s = __ffsll((unsigned long long)m0) - 1;
    m0 &= m0 - 1;
    int t = __shfl(t0, s, 64);
    float sc = scales[t];
    uint2 v = *(const uint2*)&embed_i8[(size_t)t * EMB + c];
    const int8_t* bb = (const int8_t*)&v;
#pragma unroll
    for (int j = 0; j < 8; ++j) acc[j] += sc * (float)bb[j];
  }
  while (m1) {
    int s = __ffsll((unsigned long long)m1) - 1;
    m1 &= m1 - 1;
    int t = __shfl(t1, s, 64);
    float sc = scales[t];
    uint2 v = *(const uint2*)&embed_i8[(size_t)t * EMB + c];
    const int8_t* bb = (const int8_t*)&v;
#pragma unroll
    for (int j = 0; j < 8; ++j) acc[j] += sc * (float)bb[j];
  }

  union { __half h[8]; uint4 u; } pk;
#pragma unroll
  for (int j = 0; j < 8; ++j) pk.h[j] = __float2half(acc[j]);
  *(uint4*)&partial[(((size_t)chunk * 2 + which) * NROWS + row) * EMB + c] = pk.u;
}

// ---------------------------------------------------------------------------
// Kernel 1b: reduce 8 fp16 partials -> fp16 sums (f32 accumulate).
// ---------------------------------------------------------------------------
__global__ __launch_bounds__(256) void reduce_partial_kernel(
    const __half* __restrict__ partial, __half* __restrict__ sums_h) {
  const int NG = 2 * NROWS * EMB / 8;    // 262144 uint4 groups
  int g = blockIdx.x * 256 + threadIdx.x;
  if (g >= NG) return;
  float acc[8] = {};
  const uint4* src = (const uint4*)partial;
#pragma unroll
  for (int ch = 0; ch < NCHUNK; ++ch) {
    uint4 v = src[(size_t)ch * NG + g];
    const __half* h = (const __half*)&v;
#pragma unroll
    for (int j = 0; j < 8; ++j) acc[j] += __half2float(h[j]);
  }
  union { __half h[8]; uint4 u; } pk;
#pragma unroll
  for (int j = 0; j < 8; ++j) pk.h[j] = __float2half(acc[j]);
  ((uint4*)sums_h)[g] = pk.u;
}

// ---------------------------------------------------------------------------
// Kernel 1c (round-13 path): monolithic int8 gather + vr riders.
// ---------------------------------------------------------------------------
__global__ __launch_bounds__(256) void gather_vr_kernel(
    const int* __restrict__ add_tok, const int* __restrict__ rem_tok,
    const int8_t* __restrict__ embed_i8, const float* __restrict__ scales,
    __half* __restrict__ sums_h, float* __restrict__ vr_buf) {
  int b = blockIdx.x;
  if (b < NROWS / 2) {
    int rb = b * 2;
    int wave = threadIdx.x >> 6;
    int lane = threadIdx.x & 63;
    int row = rb + (wave & 1);
    int which = wave >> 1;
    const int* tok = (which == 0 ? add_tok : rem_tok) + (size_t)row * SEQ;
    int c = lane * 8;
    float acc[8] = {};
    for (int s = 0; s < SEQ; s += 2) {
      int t0 = tok[s], t1 = tok[s + 1];
      float s0 = scales[t0], s1 = scales[t1];
      uint2 v0 = *(const uint2*)&embed_i8[(size_t)t0 * EMB + c];
      uint2 v1 = *(const uint2*)&embed_i8[(size_t)t1 * EMB + c];
      const int8_t* b0 = (const int8_t*)&v0;
      const int8_t* b1 = (const int8_t*)&v1;
#pragma unroll
      for (int j = 0; j < 8; ++j) acc[j] += s0 * (float)b0[j];
#pragma unroll
      for (int j = 0; j < 8; ++j) acc[j] += s1 * (float)b1[j];
    }
    union { __half h[8]; uint4 u; } pk;
#pragma unroll
    for (int j = 0; j < 8; ++j) pk.h[j] = __float2half(acc[j]);
    *(uint4*)&sums_h[((size_t)which * NROWS + row) * EMB + c] = pk.u;
  } else {
    int r = b - NROWS / 2;
    U2 key42; key42.x = 0u; key42.y = 42u;
    U2 kv = tf_subkey(key42, 1u);
#pragma unroll
    for (int q = 0; q < 4; ++q) {
      int j = threadIdx.x + q * 256;
      vr_buf[(size_t)r * HID + j] =
          normal_from_bits(tf_bits32(kv, (uint32_t)(r * HID + j)));
    }
  }
}

// ---------------------------------------------------------------------------
// Kernel 2: MFMA f16 GEMM. combined[r][c] = dot(sums[c-half][r], W[c&511]).
// ---------------------------------------------------------------------------
__global__ __launch_bounds__(256) void gemm_mfma_kernel(
    const __half* __restrict__ sums_h, const __half* __restrict__ W_h,
    float* __restrict__ out) {
  int wave = threadIdx.x >> 6, lane = threadIdx.x & 63;
  int r0 = blockIdx.x * 16;
  int c0 = blockIdx.y * 256 + wave * 64;
  const __half* A = sums_h + ((c0 < 512) ? 0 : (size_t)NROWS * EMB);
  int wc0 = c0 & 511;
  int l15 = lane & 15, kg = lane >> 4;
  const _Float16* arow = (const _Float16*)&A[(size_t)(r0 + l15) * EMB];
  const _Float16* b0p  = (const _Float16*)&W_h[(size_t)(wc0 +  0 + l15) * EMB];
  const _Float16* b1p  = (const _Float16*)&W_h[(size_t)(wc0 + 16 + l15) * EMB];
  const _Float16* b2p  = (const _Float16*)&W_h[(size_t)(wc0 + 32 + l15) * EMB];
  const _Float16* b3p  = (const _Float16*)&W_h[(size_t)(wc0 + 48 + l15) * EMB];
  f32x4 acc0 = {0.f,0.f,0.f,0.f}, acc1 = acc0, acc2 = acc0, acc3 = acc0;
  for (int k0 = 0; k0 < EMB; k0 += 16) {
    int k = k0 + 4 * kg;
    f16x4 af = *(const f16x4*)&arow[k];
    f16x4 b0 = *(const f16x4*)&b0p[k];
    f16x4 b1 = *(const f16x4*)&b1p[k];
    f16x4 b2 = *(const f16x4*)&b2p[k];
    f16x4 b3 = *(const f16x4*)&b3p[k];
    acc0 = __builtin_amdgcn_mfma_f32_16x16x16f16(af, b0, acc0, 0, 0, 0);
    acc1 = __builtin_amdgcn_mfma_f32_16x16x16f16(af, b1, acc1, 0, 0, 0);
    acc2 = __builtin_amdgcn_mfma_f32_16x16x16f16(af, b2, acc2, 0, 0, 0);
    acc3 = __builtin_amdgcn_mfma_f32_16x16x16f16(af, b3, acc3, 0, 0, 0);
  }
#pragma unroll
  for (int i = 0; i < 4; ++i) {
    size_t rr = (size_t)(r0 + 4 * kg + i) * HID + c0 + l15;
    out[rr +  0] = acc0[i];
    out[rr + 16] = acc1[i];
    out[rr + 32] = acc2[i];
    out[rr + 48] = acc3[i];
  }
}

// ---------------------------------------------------------------------------
// Kernel 3: per-row finalize — mu from d_out, vr from ws, w from spec arrays.
// ---------------------------------------------------------------------------
__device__ __forceinline__ float block_reduce_sum256(float v, float* red) {
#pragma unroll
  for (int off = 32; off > 0; off >>= 1) v += __shfl_down(v, off, 64);
  if ((threadIdx.x & 63) == 0) red[threadIdx.x >> 6] = v;
  __syncthreads();
  float s = red[0] + red[1] + red[2] + red[3];
  __syncthreads();
  return s;
}

__global__ __launch_bounds__(256) void finalize_kernel(
    const float* __restrict__ spec_w, const uint32_t* __restrict__ spec_ok,
    const float* __restrict__ vr_buf, float* __restrict__ out) {
#pragma clang fp contract(off)
  __shared__ float red[4];
  int r = blockIdx.x, tid = threadIdx.x;
  U2 key42; key42.x = 0u; key42.y = 42u;
  U2 kt = tf_subkey(key42, 2u);

  float mu[4], vr[4];
#pragma unroll
  for (int q = 0; q < 4; ++q) {
    int j = tid + q * 256;
    mu[q] = out[(size_t)r * HID + j];
    vr[q] = vr_buf[(size_t)r * HID + j];
  }

  float w = 0.0f;
  int found = -1;
#pragma unroll
  for (int t = 0; t < NSPEC; ++t) {
    if (found < 0 && spec_ok[t * NROWS + r]) { w = spec_w[t * NROWS + r]; found = t; }
  }
  if (found < 0) {
    U2 K = tf_subkey(key42, 0u);
    for (int j = 0; j < NSPEC; ++j) K = tf_subkey(K, 0u);
    w = wood_seq_from(K, (uint32_t)r, NSPEC);
  }
  float trand = unit_from_bits(tf_bits32(kt, (uint32_t)r)) * 0.1f;

  float ss = mu[0]*mu[0] + mu[1]*mu[1] + mu[2]*mu[2] + mu[3]*mu[3];
  ss = block_reduce_sum256(ss, red);
  float munorm = sqrtf(ss);
  float safe = fmaxf(munorm, 1e-20f);
  float muh[4];
#pragma unroll
  for (int q = 0; q < 4; ++q) muh[q] = mu[q] / safe;
  float pp = muh[0]*vr[0] + muh[1]*vr[1] + muh[2]*vr[2] + muh[3]*vr[3];
  pp = block_reduce_sum256(pp, red);
  float ortho[4];
#pragma unroll
  for (int q = 0; q < 4; ++q) ortho[q] = vr[q] - muh[q] * pp;
  float os = ortho[0]*ortho[0] + ortho[1]*ortho[1] + ortho[2]*ortho[2] + ortho[3]*ortho[3];
  os = block_reduce_sum256(os, red);
  float on = sqrtf(os);

  float sqw = sqrtf(1.0f - w * w);
  float munoise = fminf(fmaxf(munorm, 0.0f), 13.9f) + trand;
#pragma unroll
  for (int q = 0; q < 4; ++q) {
    int j = tid + q * 256;
    float v = ortho[q] / on;
    out[(size_t)r * HID + j] = (v * sqw + muh[q] * w) * munoise;
  }
}

// ---------------------------------------------------------------------------
// Fallback path kernels (f32, round-5 behavior) — used only if ws too small
// ---------------------------------------------------------------------------
__global__ __launch_bounds__(128) void gather_sum_kernel(
    const int* __restrict__ add_tok, const int* __restrict__ rem_tok,
    const float* __restrict__ embed, float* __restrict__ sums) {
  int rb = blockIdx.x * GR;
  int which = blockIdx.y;
  const int* tok = (which == 0 ? add_tok : rem_tok);
  __shared__ int t[GR][SEQ];
  for (int q = threadIdx.x; q < GR * SEQ; q += 128) {
    int rr = q >> 7, ss = q & 127;
    t[rr][ss] = tok[(size_t)(rb + rr) * SEQ + ss];
  }
  __syncthreads();
  int c = threadIdx.x * 4;
  float4 a0 = make_float4(0.f,0.f,0.f,0.f), a1 = a0, a2 = a0, a3 = a0;
  for (int s = 0; s < SEQ; ++s) {
    float4 v0 = *(const float4*)&embed[(size_t)t[0][s] * EMB + c];
    float4 v1 = *(const float4*)&embed[(size_t)t[1][s] * EMB + c];
    float4 v2 = *(const float4*)&embed[(size_t)t[2][s] * EMB + c];
    float4 v3 = *(const float4*)&embed[(size_t)t[3][s] * EMB + c];
    a0.x += v0.x; a0.y += v0.y; a0.z += v0.z; a0.w += v0.w;
    a1.x += v1.x; a1.y += v1.y; a1.z += v1.z; a1.w += v1.w;
    a2.x += v2.x; a2.y += v2.y; a2.z += v2.z; a2.w += v2.w;
    a3.x += v3.x; a3.y += v3.y; a3.z += v3.z; a3.w += v3.w;
  }
  size_t base = ((size_t)which * NROWS + rb) * EMB + c;
  *(float4*)&sums[base + 0 * EMB] = a0;
  *(float4*)&sums[base + 1 * EMB] = a1;
  *(float4*)&sums[base + 2 * EMB] = a2;
  *(float4*)&sums[base + 3 * EMB] = a3;
}

__global__ __launch_bounds__(256) void gemm_kernel(
    const float* __restrict__ sums, const float* __restrict__ W,
    float* __restrict__ out) {
  __shared__ float As[16][64];
  __shared__ float Bs[16][64];
  int r0 = blockIdx.x * 64;
  int c0 = blockIdx.y * 64;
  const float* A = sums + ((c0 < 512) ? 0 : (size_t)NROWS * EMB);
  int wc0 = c0 & 511;
  int tid = threadIdx.x;
  int tx = tid & 15, ty = tid >> 4;
  int lr = tid >> 2, lk = (tid & 3) * 4;
  float acc[4][4] = {};
  for (int k0 = 0; k0 < EMB; k0 += 16) {
    float4 av = *(const float4*)&A[(size_t)(r0 + lr) * EMB + k0 + lk];
    float4 bv = *(const float4*)&W[(size_t)(wc0 + lr) * EMB + k0 + lk];
    __syncthreads();
    As[lk + 0][lr] = av.x; As[lk + 1][lr] = av.y; As[lk + 2][lr] = av.z; As[lk + 3][lr] = av.w;
    Bs[lk + 0][lr] = bv.x; Bs[lk + 1][lr] = bv.y; Bs[lk + 2][lr] = bv.z; Bs[lk + 3][lr] = bv.w;
    __syncthreads();
#pragma unroll
    for (int kk = 0; kk < 16; ++kk) {
      float a[4], b[4];
#pragma unroll
      for (int m = 0; m < 4; ++m) a[m] = As[kk][ty * 4 + m];
#pragma unroll
      for (int n = 0; n < 4; ++n) b[n] = Bs[kk][tx * 4 + n];
#pragma unroll
      for (int m = 0; m < 4; ++m)
#pragma unroll
        for (int n = 0; n < 4; ++n) acc[m][n] += a[m] * b[n];
    }
  }
#pragma unroll
  for (int m = 0; m < 4; ++m)
#pragma unroll
    for (int n = 0; n < 4; ++n)
      out[(size_t)(r0 + ty * 4 + m) * HID + c0 + tx * 4 + n] = acc[m][n];
}

// fallback finalize with inline sequential wood + inline normals
__global__ __launch_bounds__(256) void finalize_inline_kernel(float* __restrict__ out) {
#pragma clang fp contract(off)
  __shared__ float red[4];
  int r = blockIdx.x, tid = threadIdx.x;
  U2 key42; key42.x = 0u; key42.y = 42u;
  U2 kv = tf_subkey(key42, 1u);
  U2 kt = tf_subkey(key42, 2u);

  float mu[4], vr[4];
#pragma unroll
  for (int q = 0; q < 4; ++q) {
    int j = tid + q * 256;
    mu[q] = out[(size_t)r * HID + j];
    vr[q] = normal_from_bits(tf_bits32(kv, (uint32_t)(r * HID + j)));
  }
  U2 kw = tf_subkey(key42, 0u);
  float w = wood_seq_from(kw, (uint32_t)r, 0);
  float trand = unit_from_bits(tf_bits32(kt, (uint32_t)r)) * 0.1f;

  float ss = mu[0]*mu[0] + mu[1]*mu[1] + mu[2]*mu[2] + mu[3]*mu[3];
  ss = block_reduce_sum256(ss, red);
  float munorm = sqrtf(ss);
  float safe = fmaxf(munorm, 1e-20f);
  float muh[4];
#pragma unroll
  for (int q = 0; q < 4; ++q) muh[q] = mu[q] / safe;
  float pp = muh[0]*vr[0] + muh[1]*vr[1] + muh[2]*vr[2] + muh[3]*vr[3];
  pp = block_reduce_sum256(pp, red);
  float ortho[4];
#pragma unroll
  for (int q = 0; q < 4; ++q) ortho[q] = vr[q] - muh[q] * pp;
  float os = ortho[0]*ortho[0] + ortho[1]*ortho[1] + ortho[2]*ortho[2] + ortho[3]*ortho[3];
  os = block_reduce_sum256(os, red);
  float on = sqrtf(os);

  float sqw = sqrtf(1.0f - w * w);
  float munoise = fminf(fmaxf(munorm, 0.0f), 13.9f) + trand;
#pragma unroll
  for (int q = 0; q < 4; ++q) {
    int j = tid + q * 256;
    float v = ortho[q] / on;
    out[(size_t)r * HID + j] = (v * sqw + muh[q] * w) * munoise;
  }
}

// ---------------------------------------------------------------------------
extern "C" void kernel_launch(void* const* d_in, const int* in_sizes, int n_in,
                              void* d_out, int out_size, void* d_ws, size_t ws_size,
                              hipStream_t stream) {
  const int*   add_tok = (const int*)d_in[0];
  const int*   rem_tok = (const int*)d_in[1];
  const float* embed   = (const float*)d_in[2];
  const float* W       = (const float*)d_in[3];
  float* out = (float*)d_out;

  const size_t EMBED_I8_BYTES = (size_t)VOCAB * EMB;                      // 25,731,584
  const size_t SCALE_BYTES    = (size_t)((VOCAB + 63) & ~63) * 4;         //    201,280
  const size_t W_H_BYTES      = (size_t)512 * EMB * sizeof(__half);       //    524,288
  const size_t SUMS_H_BYTES   = (size_t)2 * NROWS * EMB * sizeof(__half); //  4,194,304
  const size_t SPEC_BYTES     = (size_t)NSPEC * NROWS * 4;                //     65,536
  const size_t VR_BYTES       = (size_t)NROWS * HID * sizeof(float);      //  8,388,608
  const size_t PART_BYTES     = (size_t)NCHUNK * 2 * NROWS * EMB * 2;     // 33,554,432
  const size_t NEED_R13   = EMBED_I8_BYTES + SCALE_BYTES + W_H_BYTES + SUMS_H_BYTES
                          + 2 * SPEC_BYTES + VR_BYTES;                    // ~39.1 MB
  const size_t NEED_CHUNK = NEED_R13 + PART_BYTES;                        // ~72.7 MB

  if (ws_size >= NEED_R13) {
    char* p = (char*)d_ws;
    int8_t*   embed_i8 = (int8_t*)p;   p += EMBED_I8_BYTES;
    float*    scales   = (float*)p;    p += SCALE_BYTES;
    __half*   W_h      = (__half*)p;   p += W_H_BYTES;
    __half*   sums_h   = (__half*)p;   p += SUMS_H_BYTES;
    float*    spec_w   = (float*)p;    p += SPEC_BYTES;
    uint32_t* spec_ok  = (uint32_t*)p; p += SPEC_BYTES;
    float*    vr_buf   = (float*)p;    p += VR_BYTES;

    if (ws_size >= NEED_CHUNK) {
      __half* partial = (__half*)p;
      convert_kernel<<<NWOODBLK + NROWS + NBLK_W + NBLK_E, 256, 0, stream>>>(
          embed, W, embed_i8, scales, W_h, spec_w, spec_ok, vr_buf, NROWS);
      gather_chunk_kernel<<<(NROWS / 2) * NCHUNK, 256, 0, stream>>>(
          add_tok, rem_tok, embed_i8, scales, partial);
      reduce_partial_kernel<<<(2 * NROWS * EMB / 8 + 255) / 256, 256, 0, stream>>>(
          partial, sums_h);
    } else {
      convert_kernel<<<NWOODBLK + NBLK_W + NBLK_E, 256, 0, stream>>>(
          embed, W, embed_i8, scales, W_h, spec_w, spec_ok, vr_buf, 0);
      gather_vr_kernel<<<NROWS / 2 + NROWS, 256, 0, stream>>>(
          add_tok, rem_tok, embed_i8, scales, sums_h, vr_buf);
    }
    gemm_mfma_kernel<<<dim3(NROWS / 16, HID / 256), 256, 0, stream>>>(sums_h, W_h, out);
    finalize_kernel<<<NROWS, 256, 0, stream>>>(spec_w, spec_ok, vr_buf, out);
  } else {
    float* sums = (float*)d_ws;
    gather_sum_kernel<<<dim3(NROWS / GR, 2), 128, 0, stream>>>(add_tok, rem_tok, embed, sums);
    gemm_kernel<<<dim3(NROWS / 64, HID / 64), 256, 0, stream>>>(sums, W, out);
    finalize_inline_kernel<<<NROWS, 256, 0, stream>>>(out);
  }
}

// Round 16
// 122.244 us; speedup vs baseline: 1.8867x; 1.0244x over previous
//
#include <hip/hip_runtime.h>
#include <hip/hip_fp16.h>
#include <stdint.h>
#include <math.h>

// Problem constants
#define NROWS 2048
#define SEQ   128
#define EMB   512
#define HID   1024
#define VOCAB 50257
#define GR    4      // fallback gather: rows per block
#define NSPEC 8      // speculative Wood iterations
#define NCHUNK 8     // vocab chunks (one per XCD)

typedef _Float16 f16x4 __attribute__((ext_vector_type(4)));
typedef float    f32x4 __attribute__((ext_vector_type(4)));

// ---------------------------------------------------------------------------
// threefry2x32 (JAX PRNG), exact
// ---------------------------------------------------------------------------
struct U2 { uint32_t x, y; };

__device__ __forceinline__ uint32_t rotl32(uint32_t v, int r) {
  return (v << r) | (v >> (32 - r));
}

__device__ __forceinline__ U2 tf2x32(U2 key, uint32_t x0, uint32_t x1) {
  uint32_t ks0 = key.x, ks1 = key.y;
  uint32_t ks2 = ks0 ^ ks1 ^ 0x1BD11BDAu;
  x0 += ks0; x1 += ks1;
  x0 += x1; x1 = rotl32(x1, 13); x1 ^= x0;
  x0 += x1; x1 = rotl32(x1, 15); x1 ^= x0;
  x0 += x1; x1 = rotl32(x1, 26); x1 ^= x0;
  x0 += x1; x1 = rotl32(x1, 6);  x1 ^= x0;
  x0 += ks1; x1 += ks2 + 1u;
  x0 += x1; x1 = rotl32(x1, 17); x1 ^= x0;
  x0 += x1; x1 = rotl32(x1, 29); x1 ^= x0;
  x0 += x1; x1 = rotl32(x1, 16); x1 ^= x0;
  x0 += x1; x1 = rotl32(x1, 24); x1 ^= x0;
  x0 += ks2; x1 += ks0 + 2u;
  x0 += x1; x1 = rotl32(x1, 13); x1 ^= x0;
  x0 += x1; x1 = rotl32(x1, 15); x1 ^= x0;
  x0 += x1; x1 = rotl32(x1, 26); x1 ^= x0;
  x0 += x1; x1 = rotl32(x1, 6);  x1 ^= x0;
  x0 += ks0; x1 += ks1 + 3u;
  x0 += x1; x1 = rotl32(x1, 17); x1 ^= x0;
  x0 += x1; x1 = rotl32(x1, 29); x1 ^= x0;
  x0 += x1; x1 = rotl32(x1, 16); x1 ^= x0;
  x0 += x1; x1 = rotl32(x1, 24); x1 ^= x0;
  x0 += ks1; x1 += ks2 + 4u;
  x0 += x1; x1 = rotl32(x1, 13); x1 ^= x0;
  x0 += x1; x1 = rotl32(x1, 15); x1 ^= x0;
  x0 += x1; x1 = rotl32(x1, 26); x1 ^= x0;
  x0 += x1; x1 = rotl32(x1, 6);  x1 ^= x0;
  x0 += ks2; x1 += ks0 + 5u;
  U2 r; r.x = x0; r.y = x1; return r;
}

__device__ __forceinline__ U2 tf_subkey(U2 key, uint32_t i) { return tf2x32(key, 0u, i); }
__device__ __forceinline__ uint32_t tf_bits32(U2 key, uint32_t idx) {
  U2 r = tf2x32(key, 0u, idx);
  return r.x ^ r.y;
}

__device__ __forceinline__ float unit_from_bits(uint32_t b) {
  uint32_t fb = (b >> 9) | 0x3f800000u;
  return __uint_as_float(fb) - 1.0f;
}

__device__ __forceinline__ float f32_log(float x)  { return (float)log((double)x); }
__device__ __forceinline__ float f32_exp(float x)  { return (float)exp((double)x); }
__device__ __forceinline__ float f32_log1p(float x){ return (float)log1p((double)x); }

// XLA ErfInv f32 (Giles polynomial) — exact op order, no FMA contraction
__device__ float erfinv32(float x) {
#pragma clang fp contract(off)
  float nxx = -(x * x);
  float w = -f32_log1p(nxx);
  float p;
  if (w < 5.0f) {
    w = w - 2.5f;
    p = 2.81022636e-08f;
    p = 3.43273939e-07f  + p * w;
    p = -3.5233877e-06f  + p * w;
    p = -4.39150654e-06f + p * w;
    p = 0.00021858087f   + p * w;
    p = -0.00125372503f  + p * w;
    p = -0.00417768164f  + p * w;
    p = 0.246640727f     + p * w;
    p = 1.50140941f      + p * w;
  } else {
    w = sqrtf(w) - 3.0f;
    p = -0.000200214257f;
    p = 0.000100950558f  + p * w;
    p = 0.00134934322f   + p * w;
    p = -0.00367342844f  + p * w;
    p = 0.00573950773f   + p * w;
    p = -0.0076224613f   + p * w;
    p = 0.00943887047f   + p * w;
    p = 1.00167406f      + p * w;
    p = 2.83297682f      + p * w;
  }
  return p * x;
}

__device__ __forceinline__ float normal_from_bits(uint32_t bits) {
#pragma clang fp contract(off)
  float u = unit_from_bits(bits);
  const float LO = -0.99999994f;
  float x = u * 2.0f + LO;
  x = fmaxf(LO, x);
  return 1.4142135623730951f * erfinv32(x);
}

// jax _gamma_one(key, alpha=511.5, log_space=True): returns log(d) + log(V)
__device__ float loggamma_511_5(U2 gkey) {
#pragma clang fp contract(off)
  const float one_third = 1.0f / 3.0f;
  const float d = 511.5f - one_third;
  const float c = one_third / sqrtf(d);   // JAX: one_over_three / lax.sqrt(d)
  U2 key = tf_subkey(gkey, 0u);           // boost subkey unused for alpha>=1
  float V = 1.0f;
  for (int it = 0; it < 64; ++it) {
    U2 knext = tf_subkey(key, 0u);
    U2 xkey  = tf_subkey(key, 1u);
    U2 Ukey  = tf_subkey(key, 2u);
    float x, v;
    U2 xk = xkey;
    do {
      U2 xk_next = tf_subkey(xk, 0u);
      U2 nsub    = tf_subkey(xk, 1u);
      x = normal_from_bits(tf_bits32(nsub, 0u));
      v = 1.0f + x * c;
      xk = xk_next;
    } while (v <= 0.0f);
    float X = x * x;
    V = (v * v) * v;
    float U = unit_from_bits(tf_bits32(Ukey, 0u));
    float sq = 1.0f - 0.0331f * (X * X);
    bool cont;
    if (!(U >= sq)) {
      cont = false;
    } else {
      float logU = f32_log(U);
      float thr = X * 0.5f + d * ((1.0f - V) + f32_log(V));
      cont = (logU >= thr);
    }
    if (!cont) break;
    key = knext;
  }
  return f32_log(d) + f32_log(V);
}

__device__ float beta_elem(U2 k1, uint32_t i) {
#pragma clang fp contract(off)
  U2 ka = tf_subkey(k1, 0u);
  U2 kb = tf_subkey(k1, 1u);
  U2 ga = tf_subkey(ka, i);
  U2 gb = tf_subkey(kb, i);
  float lga = loggamma_511_5(ga);
  float lgb = loggamma_511_5(gb);
  float m  = fmaxf(lga, lgb);
  float ea = f32_exp(lga - m);
  float eb = f32_exp(lgb - m);
  return ea / (ea + eb);
}

// one Wood rejection iteration at chain key K for row i
__device__ __forceinline__ bool wood_try(U2 K, uint32_t i, float& wn) {
#pragma clang fp contract(off)
  const double kappa_d = 80.0, dimr_d = 1023.0;
  const double b_d = dimr_d / (sqrt(4.0 * kappa_d * kappa_d + dimr_d * dimr_d) + 2.0 * kappa_d);
  const double x_d = (1.0 - b_d) / (1.0 + b_d);
  const double c_d = kappa_d * x_d + dimr_d * log(1.0 - x_d * x_d);
  const float bf = (float)b_d, xf = (float)x_d, cf = (float)c_d;
  const float b1p = 1.0f + bf, b1m = 1.0f - bf;

  U2 k1 = tf_subkey(K, 1u);
  U2 k2 = tf_subkey(K, 2u);
  float z = beta_elem(k1, i);
  wn = (1.0f - b1p * z) / (1.0f - b1m * z);
  float u = unit_from_bits(tf_bits32(k2, i));
  float lhs = (80.0f * wn + 1023.0f * f32_log(1.0f - xf * wn)) - cf;
  return lhs >= f32_log(u);
}

// sequential Wood from iteration t_start (chain key K at depth t_start)
__device__ float wood_seq_from(U2 K, uint32_t i, int t_start) {
  float w = 0.0f;
  for (int t = t_start; t < 64; ++t) {
    U2 Kn = tf_subkey(K, 0u);
    float wn;
    if (wood_try(K, i, wn)) { w = wn; break; }
    K = Kn;
  }
  return w;
}

// ---------------------------------------------------------------------------
// Kernel 0: dense streaming convert (int8 table + scales + W fp16) + wood spec.
// ---------------------------------------------------------------------------
#define NWOODBLK 64
#define NBLK_W   128
#define NBLK_E   ((VOCAB + 3) / 4)    // 12565 (one wave = one vocab row)

__device__ __forceinline__ uint2 cvt4h(float4 a) {
  union { __half h[4]; uint2 u; } pk;
  pk.h[0] = __float2half(a.x); pk.h[1] = __float2half(a.y);
  pk.h[2] = __float2half(a.z); pk.h[3] = __float2half(a.w);
  return pk.u;
}

__device__ __forceinline__ uint32_t quant4(float4 a, float inv) {
  int q0 = __float2int_rn(a.x * inv);
  int q1 = __float2int_rn(a.y * inv);
  int q2 = __float2int_rn(a.z * inv);
  int q3 = __float2int_rn(a.w * inv);
  q0 = max(-127, min(127, q0)); q1 = max(-127, min(127, q1));
  q2 = max(-127, min(127, q2)); q3 = max(-127, min(127, q3));
  return (uint32_t)(uint8_t)q0 | ((uint32_t)(uint8_t)q1 << 8) |
         ((uint32_t)(uint8_t)q2 << 16) | ((uint32_t)(uint8_t)q3 << 24);
}

__global__ __launch_bounds__(256) void convert_kernel(
    const float* __restrict__ embed, const float* __restrict__ W,
    int8_t* __restrict__ embed_i8, float* __restrict__ scales,
    __half* __restrict__ W_h,
    float* __restrict__ spec_w, uint32_t* __restrict__ spec_ok) {
  int b = blockIdx.x;
  int wave = threadIdx.x >> 6, lane = threadIdx.x & 63;
  if (b < NWOODBLK) {
    int g = b * 256 + threadIdx.x;      // 0..16383
    int t = g >> 11;                    // spec iteration 0..7
    int i = g & (NROWS - 1);            // row
    U2 key42; key42.x = 0u; key42.y = 42u;
    U2 K = tf_subkey(key42, 0u);        // kw = K_0
    for (int j = 0; j < t; ++j) K = tf_subkey(K, 0u);
    float wn;
    bool ok = wood_try(K, (uint32_t)i, wn);
    spec_w[t * NROWS + i]  = wn;
    spec_ok[t * NROWS + i] = ok ? 1u : 0u;
  } else if (b < NWOODBLK + NBLK_W) {
    int wid = (b - NWOODBLK) * 4 + wave;          // 0..511
    size_t base = (size_t)wid * 128 + lane;
    const float4* src = (const float4*)W;
    uint2* dst = (uint2*)W_h;
    float4 a = src[base];
    float4 c = src[base + 64];
    dst[base]      = cvt4h(a);
    dst[base + 64] = cvt4h(c);
  } else {
    int wid = (b - NWOODBLK - NBLK_W) * 4 + wave; // vocab row
    if (wid < VOCAB) {
      size_t base = (size_t)wid * 128 + lane;     // float4 index
      const float4* src = (const float4*)embed;
      float4 a = src[base];
      float4 c = src[base + 64];
      float m = fmaxf(fmaxf(fmaxf(fabsf(a.x), fabsf(a.y)), fmaxf(fabsf(a.z), fabsf(a.w))),
                      fmaxf(fmaxf(fabsf(c.x), fabsf(c.y)), fmaxf(fabsf(c.z), fabsf(c.w))));
#pragma unroll
      for (int off = 1; off < 64; off <<= 1) m = fmaxf(m, __shfl_xor(m, off, 64));
      float inv   = (m > 0.0f) ? 127.0f / m : 0.0f;
      float scale = (m > 0.0f) ? m / 127.0f : 0.0f;
      uint32_t* dst = (uint32_t*)embed_i8;
      size_t b32 = (size_t)wid * 128 + lane;      // uint32 index (4 bytes each)
      dst[b32]      = quant4(a, inv);
      dst[b32 + 64] = quant4(c, inv);
      if (lane == 0) scales[wid] = scale;
    }
  }
}

// ---------------------------------------------------------------------------
// Kernel 1a (chunked v3): ballot-compacted gather with 4-way MLP hit loop,
// plus vr-rider blocks [8192, 8192+2048) hidden behind the gather.
// Accumulation order = ascending bit order (deterministic, same as v2).
// ---------------------------------------------------------------------------
__global__ __launch_bounds__(256) void gather_chunk_kernel(
    const int* __restrict__ add_tok, const int* __restrict__ rem_tok,
    const int8_t* __restrict__ embed_i8, const float* __restrict__ scales,
    __half* __restrict__ partial, float* __restrict__ vr_buf) {
  int bid = blockIdx.x;
  if (bid >= (NROWS / 2) * NCHUNK) {
    // v_raw normals rider (input-independent, key 42)
    int r = bid - (NROWS / 2) * NCHUNK;   // 0..2047
    U2 key42; key42.x = 0u; key42.y = 42u;
    U2 kv = tf_subkey(key42, 1u);
#pragma unroll
    for (int q = 0; q < 4; ++q) {
      int j = threadIdx.x + q * 256;
      vr_buf[(size_t)r * HID + j] =
          normal_from_bits(tf_bits32(kv, (uint32_t)(r * HID + j)));
    }
    return;
  }
  int chunk = bid & (NCHUNK - 1);
  int rp = bid >> 3;
  int wave = threadIdx.x >> 6, lane = threadIdx.x & 63;
  int row = rp * 2 + (wave & 1);
  int which = wave >> 1;
  const int lo = (chunk * VOCAB) / NCHUNK;
  const int hi = ((chunk + 1) * VOCAB) / NCHUNK;
  const int* tok = (which == 0 ? add_tok : rem_tok) + (size_t)row * SEQ;
  int c = lane * 8;

  int t0 = tok[lane];
  int t1 = tok[lane + 64];
  unsigned long long m0 = __ballot(t0 >= lo && t0 < hi);
  unsigned long long m1 = __ballot(t1 >= lo && t1 < hi);

  float acc[8] = {};
#pragma unroll 1
  for (int half = 0; half < 2; ++half) {
    unsigned long long m = half == 0 ? m0 : m1;
    int tsrc = half == 0 ? t0 : t1;
    while (m) {
      // extract up to 4 hits (wave-uniform), issue all loads, then accumulate
      int n = 1;
      int s0 = __ffsll(m) - 1; m &= m - 1;
      int s1 = 0, s2 = 0, s3 = 0;
      if (m) { s1 = __ffsll(m) - 1; m &= m - 1; n = 2;
        if (m) { s2 = __ffsll(m) - 1; m &= m - 1; n = 3;
          if (m) { s3 = __ffsll(m) - 1; m &= m - 1; n = 4; } } }
      int tA = __shfl(tsrc, s0, 64);
      int tB = __shfl(tsrc, s1, 64);
      int tC = __shfl(tsrc, s2, 64);
      int tD = __shfl(tsrc, s3, 64);
      float scA = scales[tA];
      uint2  vA = *(const uint2*)&embed_i8[(size_t)tA * EMB + c];
      float scB = 0.f; uint2 vB = {0u, 0u};
      float scC = 0.f; uint2 vC = {0u, 0u};
      float scD = 0.f; uint2 vD = {0u, 0u};
      if (n > 1) { scB = scales[tB]; vB = *(const uint2*)&embed_i8[(size_t)tB * EMB + c]; }
      if (n > 2) { scC = scales[tC]; vC = *(const uint2*)&embed_i8[(size_t)tC * EMB + c]; }
      if (n > 3) { scD = scales[tD]; vD = *(const uint2*)&embed_i8[(size_t)tD * EMB + c]; }
      const int8_t* bA = (const int8_t*)&vA;
#pragma unroll
      for (int j = 0; j < 8; ++j) acc[j] += scA * (float)bA[j];
      if (n > 1) {
        const int8_t* bB = (const int8_t*)&vB;
#pragma unroll
        for (int j = 0; j < 8; ++j) acc[j] += scB * (float)bB[j];
      }
      if (n > 2) {
        const int8_t* bC = (const int8_t*)&vC;
#pragma unroll
        for (int j = 0; j < 8; ++j) acc[j] += scC * (float)bC[j];
      }
      if (n > 3) {
        const int8_t* bD = (const int8_t*)&vD;
#pragma unroll
        for (int j = 0; j < 8; ++j) acc[j] += scD * (float)bD[j];
      }
    }
  }

  union { __half h[8]; uint4 u; } pk;
#pragma unroll
  for (int j = 0; j < 8; ++j) pk.h[j] = __float2half(acc[j]);
  *(uint4*)&partial[(((size_t)chunk * 2 + which) * NROWS + row) * EMB + c] = pk.u;
}

// ---------------------------------------------------------------------------
// Kernel 1b: reduce 8 fp16 partials -> fp16 sums (f32 accumulate).
// ---------------------------------------------------------------------------
__global__ __launch_bounds__(256) void reduce_partial_kernel(
    const __half* __restrict__ partial, __half* __restrict__ sums_h) {
  const int NG = 2 * NROWS * EMB / 8;    // 262144 uint4 groups
  int g = blockIdx.x * 256 + threadIdx.x;
  if (g >= NG) return;
  float acc[8] = {};
  const uint4* src = (const uint4*)partial;
#pragma unroll
  for (int ch = 0; ch < NCHUNK; ++ch) {
    uint4 v = src[(size_t)ch * NG + g];
    const __half* h = (const __half*)&v;
#pragma unroll
    for (int j = 0; j < 8; ++j) acc[j] += __half2float(h[j]);
  }
  union { __half h[8]; uint4 u; } pk;
#pragma unroll
  for (int j = 0; j < 8; ++j) pk.h[j] = __float2half(acc[j]);
  ((uint4*)sums_h)[g] = pk.u;
}

// ---------------------------------------------------------------------------
// Kernel 1c (round-13 path): monolithic int8 gather + vr riders.
// ---------------------------------------------------------------------------
__global__ __launch_bounds__(256) void gather_vr_kernel(
    const int* __restrict__ add_tok, const int* __restrict__ rem_tok,
    const int8_t* __restrict__ embed_i8, const float* __restrict__ scales,
    __half* __restrict__ sums_h, float* __restrict__ vr_buf) {
  int b = blockIdx.x;
  if (b < NROWS / 2) {
    int rb = b * 2;
    int wave = threadIdx.x >> 6;
    int lane = threadIdx.x & 63;
    int row = rb + (wave & 1);
    int which = wave >> 1;
    const int* tok = (which == 0 ? add_tok : rem_tok) + (size_t)row * SEQ;
    int c = lane * 8;
    float acc[8] = {};
    for (int s = 0; s < SEQ; s += 2) {
      int t0 = tok[s], t1 = tok[s + 1];
      float s0 = scales[t0], s1 = scales[t1];
      uint2 v0 = *(const uint2*)&embed_i8[(size_t)t0 * EMB + c];
      uint2 v1 = *(const uint2*)&embed_i8[(size_t)t1 * EMB + c];
      const int8_t* b0 = (const int8_t*)&v0;
      const int8_t* b1 = (const int8_t*)&v1;
#pragma unroll
      for (int j = 0; j < 8; ++j) acc[j] += s0 * (float)b0[j];
#pragma unroll
      for (int j = 0; j < 8; ++j) acc[j] += s1 * (float)b1[j];
    }
    union { __half h[8]; uint4 u; } pk;
#pragma unroll
    for (int j = 0; j < 8; ++j) pk.h[j] = __float2half(acc[j]);
    *(uint4*)&sums_h[((size_t)which * NROWS + row) * EMB + c] = pk.u;
  } else {
    int r = b - NROWS / 2;
    U2 key42; key42.x = 0u; key42.y = 42u;
    U2 kv = tf_subkey(key42, 1u);
#pragma unroll
    for (int q = 0; q < 4; ++q) {
      int j = threadIdx.x + q * 256;
      vr_buf[(size_t)r * HID + j] =
          normal_from_bits(tf_bits32(kv, (uint32_t)(r * HID + j)));
    }
  }
}

// ---------------------------------------------------------------------------
// Kernel 2: MFMA f16 GEMM. combined[r][c] = dot(sums[c-half][r], W[c&511]).
// ---------------------------------------------------------------------------
__global__ __launch_bounds__(256) void gemm_mfma_kernel(
    const __half* __restrict__ sums_h, const __half* __restrict__ W_h,
    float* __restrict__ out) {
  int wave = threadIdx.x >> 6, lane = threadIdx.x & 63;
  int r0 = blockIdx.x * 16;
  int c0 = blockIdx.y * 256 + wave * 64;
  const __half* A = sums_h + ((c0 < 512) ? 0 : (size_t)NROWS * EMB);
  int wc0 = c0 & 511;
  int l15 = lane & 15, kg = lane >> 4;
  const _Float16* arow = (const _Float16*)&A[(size_t)(r0 + l15) * EMB];
  const _Float16* b0p  = (const _Float16*)&W_h[(size_t)(wc0 +  0 + l15) * EMB];
  const _Float16* b1p  = (const _Float16*)&W_h[(size_t)(wc0 + 16 + l15) * EMB];
  const _Float16* b2p  = (const _Float16*)&W_h[(size_t)(wc0 + 32 + l15) * EMB];
  const _Float16* b3p  = (const _Float16*)&W_h[(size_t)(wc0 + 48 + l15) * EMB];
  f32x4 acc0 = {0.f,0.f,0.f,0.f}, acc1 = acc0, acc2 = acc0, acc3 = acc0;
  for (int k0 = 0; k0 < EMB; k0 += 16) {
    int k = k0 + 4 * kg;
    f16x4 af = *(const f16x4*)&arow[k];
    f16x4 b0 = *(const f16x4*)&b0p[k];
    f16x4 b1 = *(const f16x4*)&b1p[k];
    f16x4 b2 = *(const f16x4*)&b2p[k];
    f16x4 b3 = *(const f16x4*)&b3p[k];
    acc0 = __builtin_amdgcn_mfma_f32_16x16x16f16(af, b0, acc0, 0, 0, 0);
    acc1 = __builtin_amdgcn_mfma_f32_16x16x16f16(af, b1, acc1, 0, 0, 0);
    acc2 = __builtin_amdgcn_mfma_f32_16x16x16f16(af, b2, acc2, 0, 0, 0);
    acc3 = __builtin_amdgcn_mfma_f32_16x16x16f16(af, b3, acc3, 0, 0, 0);
  }
#pragma unroll
  for (int i = 0; i < 4; ++i) {
    size_t rr = (size_t)(r0 + 4 * kg + i) * HID + c0 + l15;
    out[rr +  0] = acc0[i];
    out[rr + 16] = acc1[i];
    out[rr + 32] = acc2[i];
    out[rr + 48] = acc3[i];
  }
}

// ---------------------------------------------------------------------------
// Kernel 3: per-row finalize — mu from d_out, vr from ws, w from spec arrays.
// ---------------------------------------------------------------------------
__device__ __forceinline__ float block_reduce_sum256(float v, float* red) {
#pragma unroll
  for (int off = 32; off > 0; off >>= 1) v += __shfl_down(v, off, 64);
  if ((threadIdx.x & 63) == 0) red[threadIdx.x >> 6] = v;
  __syncthreads();
  float s = red[0] + red[1] + red[2] + red[3];
  __syncthreads();
  return s;
}

__global__ __launch_bounds__(256) void finalize_kernel(
    const float* __restrict__ spec_w, const uint32_t* __restrict__ spec_ok,
    const float* __restrict__ vr_buf, float* __restrict__ out) {
#pragma clang fp contract(off)
  __shared__ float red[4];
  int r = blockIdx.x, tid = threadIdx.x;
  U2 key42; key42.x = 0u; key42.y = 42u;
  U2 kt = tf_subkey(key42, 2u);

  float mu[4], vr[4];
#pragma unroll
  for (int q = 0; q < 4; ++q) {
    int j = tid + q * 256;
    mu[q] = out[(size_t)r * HID + j];
    vr[q] = vr_buf[(size_t)r * HID + j];
  }

  float w = 0.0f;
  int found = -1;
#pragma unroll
  for (int t = 0; t < NSPEC; ++t) {
    if (found < 0 && spec_ok[t * NROWS + r]) { w = spec_w[t * NROWS + r]; found = t; }
  }
  if (found < 0) {
    U2 K = tf_subkey(key42, 0u);
    for (int j = 0; j < NSPEC; ++j) K = tf_subkey(K, 0u);
    w = wood_seq_from(K, (uint32_t)r, NSPEC);
  }
  float trand = unit_from_bits(tf_bits32(kt, (uint32_t)r)) * 0.1f;

  float ss = mu[0]*mu[0] + mu[1]*mu[1] + mu[2]*mu[2] + mu[3]*mu[3];
  ss = block_reduce_sum256(ss, red);
  float munorm = sqrtf(ss);
  float safe = fmaxf(munorm, 1e-20f);
  float muh[4];
#pragma unroll
  for (int q = 0; q < 4; ++q) muh[q] = mu[q] / safe;
  float pp = muh[0]*vr[0] + muh[1]*vr[1] + muh[2]*vr[2] + muh[3]*vr[3];
  pp = block_reduce_sum256(pp, red);
  float ortho[4];
#pragma unroll
  for (int q = 0; q < 4; ++q) ortho[q] = vr[q] - muh[q] * pp;
  float os = ortho[0]*ortho[0] + ortho[1]*ortho[1] + ortho[2]*ortho[2] + ortho[3]*ortho[3];
  os = block_reduce_sum256(os, red);
  float on = sqrtf(os);

  float sqw = sqrtf(1.0f - w * w);
  float munoise = fminf(fmaxf(munorm, 0.0f), 13.9f) + trand;
#pragma unroll
  for (int q = 0; q < 4; ++q) {
    int j = tid + q * 256;
    float v = ortho[q] / on;
    out[(size_t)r * HID + j] = (v * sqw + muh[q] * w) * munoise;
  }
}

// ---------------------------------------------------------------------------
// Fallback path kernels (f32, round-5 behavior) — used only if ws too small
// ---------------------------------------------------------------------------
__global__ __launch_bounds__(128) void gather_sum_kernel(
    const int* __restrict__ add_tok, const int* __restrict__ rem_tok,
    const float* __restrict__ embed, float* __restrict__ sums) {
  int rb = blockIdx.x * GR;
  int which = blockIdx.y;
  const int* tok = (which == 0 ? add_tok : rem_tok);
  __shared__ int t[GR][SEQ];
  for (int q = threadIdx.x; q < GR * SEQ; q += 128) {
    int rr = q >> 7, ss = q & 127;
    t[rr][ss] = tok[(size_t)(rb + rr) * SEQ + ss];
  }
  __syncthreads();
  int c = threadIdx.x * 4;
  float4 a0 = make_float4(0.f,0.f,0.f,0.f), a1 = a0, a2 = a0, a3 = a0;
  for (int s = 0; s < SEQ; ++s) {
    float4 v0 = *(const float4*)&embed[(size_t)t[0][s] * EMB + c];
    float4 v1 = *(const float4*)&embed[(size_t)t[1][s] * EMB + c];
    float4 v2 = *(const float4*)&embed[(size_t)t[2][s] * EMB + c];
    float4 v3 = *(const float4*)&embed[(size_t)t[3][s] * EMB + c];
    a0.x += v0.x; a0.y += v0.y; a0.z += v0.z; a0.w += v0.w;
    a1.x += v1.x; a1.y += v1.y; a1.z += v1.z; a1.w += v1.w;
    a2.x += v2.x; a2.y += v2.y; a2.z += v2.z; a2.w += v2.w;
    a3.x += v3.x; a3.y += v3.y; a3.z += v3.z; a3.w += v3.w;
  }
  size_t base = ((size_t)which * NROWS + rb) * EMB + c;
  *(float4*)&sums[base + 0 * EMB] = a0;
  *(float4*)&sums[base + 1 * EMB] = a1;
  *(float4*)&sums[base + 2 * EMB] = a2;
  *(float4*)&sums[base + 3 * EMB] = a3;
}

__global__ __launch_bounds__(256) void gemm_kernel(
    const float* __restrict__ sums, const float* __restrict__ W,
    float* __restrict__ out) {
  __shared__ float As[16][64];
  __shared__ float Bs[16][64];
  int r0 = blockIdx.x * 64;
  int c0 = blockIdx.y * 64;
  const float* A = sums + ((c0 < 512) ? 0 : (size_t)NROWS * EMB);
  int wc0 = c0 & 511;
  int tid = threadIdx.x;
  int tx = tid & 15, ty = tid >> 4;
  int lr = tid >> 2, lk = (tid & 3) * 4;
  float acc[4][4] = {};
  for (int k0 = 0; k0 < EMB; k0 += 16) {
    float4 av = *(const float4*)&A[(size_t)(r0 + lr) * EMB + k0 + lk];
    float4 bv = *(const float4*)&W[(size_t)(wc0 + lr) * EMB + k0 + lk];
    __syncthreads();
    As[lk + 0][lr] = av.x; As[lk + 1][lr] = av.y; As[lk + 2][lr] = av.z; As[lk + 3][lr] = av.w;
    Bs[lk + 0][lr] = bv.x; Bs[lk + 1][lr] = bv.y; Bs[lk + 2][lr] = bv.z; Bs[lk + 3][lr] = bv.w;
    __syncthreads();
#pragma unroll
    for (int kk = 0; kk < 16; ++kk) {
      float a[4], b[4];
#pragma unroll
      for (int m = 0; m < 4; ++m) a[m] = As[kk][ty * 4 + m];
#pragma unroll
      for (int n = 0; n < 4; ++n) b[n] = Bs[kk][tx * 4 + n];
#pragma unroll
      for (int m = 0; m < 4; ++m)
#pragma unroll
        for (int n = 0; n < 4; ++n) acc[m][n] += a[m] * b[n];
    }
  }
#pragma unroll
  for (int m = 0; m < 4; ++m)
#pragma unroll
    for (int n = 0; n < 4; ++n)
      out[(size_t)(r0 + ty * 4 + m) * HID + c0 + tx * 4 + n] = acc[m][n];
}

// fallback finalize with inline sequential wood + inline normals
__global__ __launch_bounds__(256) void finalize_inline_kernel(float* __restrict__ out) {
#pragma clang fp contract(off)
  __shared__ float red[4];
  int r = blockIdx.x, tid = threadIdx.x;
  U2 key42; key42.x = 0u; key42.y = 42u;
  U2 kv = tf_subkey(key42, 1u);
  U2 kt = tf_subkey(key42, 2u);

  float mu[4], vr[4];
#pragma unroll
  for (int q = 0; q < 4; ++q) {
    int j = tid + q * 256;
    mu[q] = out[(size_t)r * HID + j];
    vr[q] = normal_from_bits(tf_bits32(kv, (uint32_t)(r * HID + j)));
  }
  U2 kw = tf_subkey(key42, 0u);
  float w = wood_seq_from(kw, (uint32_t)r, 0);
  float trand = unit_from_bits(tf_bits32(kt, (uint32_t)r)) * 0.1f;

  float ss = mu[0]*mu[0] + mu[1]*mu[1] + mu[2]*mu[2] + mu[3]*mu[3];
  ss = block_reduce_sum256(ss, red);
  float munorm = sqrtf(ss);
  float safe = fmaxf(munorm, 1e-20f);
  float muh[4];
#pragma unroll
  for (int q = 0; q < 4; ++q) muh[q] = mu[q] / safe;
  float pp = muh[0]*vr[0] + muh[1]*vr[1] + muh[2]*vr[2] + muh[3]*vr[3];
  pp = block_reduce_sum256(pp, red);
  float ortho[4];
#pragma unroll
  for (int q = 0; q < 4; ++q) ortho[q] = vr[q] - muh[q] * pp;
  float os = ortho[0]*ortho[0] + ortho[1]*ortho[1] + ortho[2]*ortho[2] + ortho[3]*ortho[3];
  os = block_reduce_sum256(os, red);
  float on = sqrtf(os);

  float sqw = sqrtf(1.0f - w * w);
  float munoise = fminf(fmaxf(munorm, 0.0f), 13.9f) + trand;
#pragma unroll
  for (int q = 0; q < 4; ++q) {
    int j = tid + q * 256;
    float v = ortho[q] / on;
    out[(size_t)r * HID + j] = (v * sqw + muh[q] * w) * munoise;
  }
}

// ---------------------------------------------------------------------------
extern "C" void kernel_launch(void* const* d_in, const int* in_sizes, int n_in,
                              void* d_out, int out_size, void* d_ws, size_t ws_size,
                              hipStream_t stream) {
  const int*   add_tok = (const int*)d_in[0];
  const int*   rem_tok = (const int*)d_in[1];
  const float* embed   = (const float*)d_in[2];
  const float* W       = (const float*)d_in[3];
  float* out = (float*)d_out;

  const size_t EMBED_I8_BYTES = (size_t)VOCAB * EMB;                      // 25,731,584
  const size_t SCALE_BYTES    = (size_t)((VOCAB + 63) & ~63) * 4;         //    201,280
  const size_t W_H_BYTES      = (size_t)512 * EMB * sizeof(__half);       //    524,288
  const size_t SUMS_H_BYTES   = (size_t)2 * NROWS * EMB * sizeof(__half); //  4,194,304
  const size_t SPEC_BYTES     = (size_t)NSPEC * NROWS * 4;                //     65,536
  const size_t VR_BYTES       = (size_t)NROWS * HID * sizeof(float);      //  8,388,608
  const size_t PART_BYTES     = (size_t)NCHUNK * 2 * NROWS * EMB * 2;     // 33,554,432
  const size_t NEED_R13   = EMBED_I8_BYTES + SCALE_BYTES + W_H_BYTES + SUMS_H_BYTES
                          + 2 * SPEC_BYTES + VR_BYTES;                    // ~39.1 MB
  const size_t NEED_CHUNK = NEED_R13 + PART_BYTES;                        // ~72.7 MB

  if (ws_size >= NEED_R13) {
    char* p = (char*)d_ws;
    int8_t*   embed_i8 = (int8_t*)p;   p += EMBED_I8_BYTES;
    float*    scales   = (float*)p;    p += SCALE_BYTES;
    __half*   W_h      = (__half*)p;   p += W_H_BYTES;
    __half*   sums_h   = (__half*)p;   p += SUMS_H_BYTES;
    float*    spec_w   = (float*)p;    p += SPEC_BYTES;
    uint32_t* spec_ok  = (uint32_t*)p; p += SPEC_BYTES;
    float*    vr_buf   = (float*)p;    p += VR_BYTES;

    convert_kernel<<<NWOODBLK + NBLK_W + NBLK_E, 256, 0, stream>>>(
        embed, W, embed_i8, scales, W_h, spec_w, spec_ok);
    if (ws_size >= NEED_CHUNK) {
      __half* partial = (__half*)p;
      gather_chunk_kernel<<<(NROWS / 2) * NCHUNK + NROWS, 256, 0, stream>>>(
          add_tok, rem_tok, embed_i8, scales, partial, vr_buf);
      reduce_partial_kernel<<<(2 * NROWS * EMB / 8 + 255) / 256, 256, 0, stream>>>(
          partial, sums_h);
    } else {
      gather_vr_kernel<<<NROWS / 2 + NROWS, 256, 0, stream>>>(
          add_tok, rem_tok, embed_i8, scales, sums_h, vr_buf);
    }
    gemm_mfma_kernel<<<dim3(NROWS / 16, HID / 256), 256, 0, stream>>>(sums_h, W_h, out);
    finalize_kernel<<<NROWS, 256, 0, stream>>>(spec_w, spec_ok, vr_buf, out);
  } else {
    float* sums = (float*)d_ws;
    gather_sum_kernel<<<dim3(NROWS / GR, 2), 128, 0, stream>>>(add_tok, rem_tok, embed, sums);
    gemm_kernel<<<dim3(NROWS / 64, HID / 64), 256, 0, stream>>>(sums, W, out);
    finalize_inline_kernel<<<NROWS, 256, 0, stream>>>(out);
  }
}

// Round 17
// 108.167 us; speedup vs baseline: 2.1322x; 1.1301x over previous
//
#include <hip/hip_runtime.h>
#include <hip/hip_fp16.h>
#include <stdint.h>
#include <math.h>

// Problem constants
#define NROWS 2048
#define SEQ   128
#define EMB   512
#define HID   1024
#define VOCAB 50257
#define GR    4      // fallback gather: rows per block
#define NSPEC 8      // speculative Wood iterations

typedef _Float16 f16x4 __attribute__((ext_vector_type(4)));
typedef float    f32x4 __attribute__((ext_vector_type(4)));

// ---------------------------------------------------------------------------
// threefry2x32 (JAX PRNG), exact
// ---------------------------------------------------------------------------
struct U2 { uint32_t x, y; };

__device__ __forceinline__ uint32_t rotl32(uint32_t v, int r) {
  return (v << r) | (v >> (32 - r));
}

__device__ __forceinline__ U2 tf2x32(U2 key, uint32_t x0, uint32_t x1) {
  uint32_t ks0 = key.x, ks1 = key.y;
  uint32_t ks2 = ks0 ^ ks1 ^ 0x1BD11BDAu;
  x0 += ks0; x1 += ks1;
  x0 += x1; x1 = rotl32(x1, 13); x1 ^= x0;
  x0 += x1; x1 = rotl32(x1, 15); x1 ^= x0;
  x0 += x1; x1 = rotl32(x1, 26); x1 ^= x0;
  x0 += x1; x1 = rotl32(x1, 6);  x1 ^= x0;
  x0 += ks1; x1 += ks2 + 1u;
  x0 += x1; x1 = rotl32(x1, 17); x1 ^= x0;
  x0 += x1; x1 = rotl32(x1, 29); x1 ^= x0;
  x0 += x1; x1 = rotl32(x1, 16); x1 ^= x0;
  x0 += x1; x1 = rotl32(x1, 24); x1 ^= x0;
  x0 += ks2; x1 += ks0 + 2u;
  x0 += x1; x1 = rotl32(x1, 13); x1 ^= x0;
  x0 += x1; x1 = rotl32(x1, 15); x1 ^= x0;
  x0 += x1; x1 = rotl32(x1, 26); x1 ^= x0;
  x0 += x1; x1 = rotl32(x1, 6);  x1 ^= x0;
  x0 += ks0; x1 += ks1 + 3u;
  x0 += x1; x1 = rotl32(x1, 17); x1 ^= x0;
  x0 += x1; x1 = rotl32(x1, 29); x1 ^= x0;
  x0 += x1; x1 = rotl32(x1, 16); x1 ^= x0;
  x0 += x1; x1 = rotl32(x1, 24); x1 ^= x0;
  x0 += ks1; x1 += ks2 + 4u;
  x0 += x1; x1 = rotl32(x1, 13); x1 ^= x0;
  x0 += x1; x1 = rotl32(x1, 15); x1 ^= x0;
  x0 += x1; x1 = rotl32(x1, 26); x1 ^= x0;
  x0 += x1; x1 = rotl32(x1, 6);  x1 ^= x0;
  x0 += ks2; x1 += ks0 + 5u;
  U2 r; r.x = x0; r.y = x1; return r;
}

__device__ __forceinline__ U2 tf_subkey(U2 key, uint32_t i) { return tf2x32(key, 0u, i); }
__device__ __forceinline__ uint32_t tf_bits32(U2 key, uint32_t idx) {
  U2 r = tf2x32(key, 0u, idx);
  return r.x ^ r.y;
}

__device__ __forceinline__ float unit_from_bits(uint32_t b) {
  uint32_t fb = (b >> 9) | 0x3f800000u;
  return __uint_as_float(fb) - 1.0f;
}

__device__ __forceinline__ float f32_log(float x)  { return (float)log((double)x); }
__device__ __forceinline__ float f32_exp(float x)  { return (float)exp((double)x); }
__device__ __forceinline__ float f32_log1p(float x){ return (float)log1p((double)x); }

// XLA ErfInv f32 (Giles polynomial) — exact op order, no FMA contraction
__device__ float erfinv32(float x) {
#pragma clang fp contract(off)
  float nxx = -(x * x);
  float w = -f32_log1p(nxx);
  float p;
  if (w < 5.0f) {
    w = w - 2.5f;
    p = 2.81022636e-08f;
    p = 3.43273939e-07f  + p * w;
    p = -3.5233877e-06f  + p * w;
    p = -4.39150654e-06f + p * w;
    p = 0.00021858087f   + p * w;
    p = -0.00125372503f  + p * w;
    p = -0.00417768164f  + p * w;
    p = 0.246640727f     + p * w;
    p = 1.50140941f      + p * w;
  } else {
    w = sqrtf(w) - 3.0f;
    p = -0.000200214257f;
    p = 0.000100950558f  + p * w;
    p = 0.00134934322f   + p * w;
    p = -0.00367342844f  + p * w;
    p = 0.00573950773f   + p * w;
    p = -0.0076224613f   + p * w;
    p = 0.00943887047f   + p * w;
    p = 1.00167406f      + p * w;
    p = 2.83297682f      + p * w;
  }
  return p * x;
}

__device__ __forceinline__ float normal_from_bits(uint32_t bits) {
#pragma clang fp contract(off)
  float u = unit_from_bits(bits);
  const float LO = -0.99999994f;
  float x = u * 2.0f + LO;
  x = fmaxf(LO, x);
  return 1.4142135623730951f * erfinv32(x);
}

// jax _gamma_one(key, alpha=511.5, log_space=True): returns log(d) + log(V)
__device__ float loggamma_511_5(U2 gkey) {
#pragma clang fp contract(off)
  const float one_third = 1.0f / 3.0f;
  const float d = 511.5f - one_third;
  const float c = one_third / sqrtf(d);   // JAX: one_over_three / lax.sqrt(d)
  U2 key = tf_subkey(gkey, 0u);           // boost subkey unused for alpha>=1
  float V = 1.0f;
  for (int it = 0; it < 64; ++it) {
    U2 knext = tf_subkey(key, 0u);
    U2 xkey  = tf_subkey(key, 1u);
    U2 Ukey  = tf_subkey(key, 2u);
    float x, v;
    U2 xk = xkey;
    do {
      U2 xk_next = tf_subkey(xk, 0u);
      U2 nsub    = tf_subkey(xk, 1u);
      x = normal_from_bits(tf_bits32(nsub, 0u));
      v = 1.0f + x * c;
      xk = xk_next;
    } while (v <= 0.0f);
    float X = x * x;
    V = (v * v) * v;
    float U = unit_from_bits(tf_bits32(Ukey, 0u));
    float sq = 1.0f - 0.0331f * (X * X);
    bool cont;
    if (!(U >= sq)) {
      cont = false;
    } else {
      float logU = f32_log(U);
      float thr = X * 0.5f + d * ((1.0f - V) + f32_log(V));
      cont = (logU >= thr);
    }
    if (!cont) break;
    key = knext;
  }
  return f32_log(d) + f32_log(V);
}

__device__ float beta_elem(U2 k1, uint32_t i) {
#pragma clang fp contract(off)
  U2 ka = tf_subkey(k1, 0u);
  U2 kb = tf_subkey(k1, 1u);
  U2 ga = tf_subkey(ka, i);
  U2 gb = tf_subkey(kb, i);
  float lga = loggamma_511_5(ga);
  float lgb = loggamma_511_5(gb);
  float m  = fmaxf(lga, lgb);
  float ea = f32_exp(lga - m);
  float eb = f32_exp(lgb - m);
  return ea / (ea + eb);
}

// one Wood rejection iteration at chain key K for row i
__device__ __forceinline__ bool wood_try(U2 K, uint32_t i, float& wn) {
#pragma clang fp contract(off)
  const double kappa_d = 80.0, dimr_d = 1023.0;
  const double b_d = dimr_d / (sqrt(4.0 * kappa_d * kappa_d + dimr_d * dimr_d) + 2.0 * kappa_d);
  const double x_d = (1.0 - b_d) / (1.0 + b_d);
  const double c_d = kappa_d * x_d + dimr_d * log(1.0 - x_d * x_d);
  const float bf = (float)b_d, xf = (float)x_d, cf = (float)c_d;
  const float b1p = 1.0f + bf, b1m = 1.0f - bf;

  U2 k1 = tf_subkey(K, 1u);
  U2 k2 = tf_subkey(K, 2u);
  float z = beta_elem(k1, i);
  wn = (1.0f - b1p * z) / (1.0f - b1m * z);
  float u = unit_from_bits(tf_bits32(k2, i));
  float lhs = (80.0f * wn + 1023.0f * f32_log(1.0f - xf * wn)) - cf;
  return lhs >= f32_log(u);
}

// sequential Wood from iteration t_start (chain key K at depth t_start)
__device__ float wood_seq_from(U2 K, uint32_t i, int t_start) {
  float w = 0.0f;
  for (int t = t_start; t < 64; ++t) {
    U2 Kn = tf_subkey(K, 0u);
    float wn;
    if (wood_try(K, i, wn)) { w = wn; break; }
    K = Kn;
  }
  return w;
}

// ---------------------------------------------------------------------------
// Kernel 0: dense streaming convert, int8 table with per-vocab-row scale.
// ---------------------------------------------------------------------------
#define NWOODBLK 64
#define NBLK_W   128
#define NBLK_E   ((VOCAB + 3) / 4)    // 12565 (one wave = one vocab row)

__device__ __forceinline__ uint2 cvt4h(float4 a) {
  union { __half h[4]; uint2 u; } pk;
  pk.h[0] = __float2half(a.x); pk.h[1] = __float2half(a.y);
  pk.h[2] = __float2half(a.z); pk.h[3] = __float2half(a.w);
  return pk.u;
}

__device__ __forceinline__ uint32_t quant4(float4 a, float inv) {
  int q0 = __float2int_rn(a.x * inv);
  int q1 = __float2int_rn(a.y * inv);
  int q2 = __float2int_rn(a.z * inv);
  int q3 = __float2int_rn(a.w * inv);
  q0 = max(-127, min(127, q0)); q1 = max(-127, min(127, q1));
  q2 = max(-127, min(127, q2)); q3 = max(-127, min(127, q3));
  return (uint32_t)(uint8_t)q0 | ((uint32_t)(uint8_t)q1 << 8) |
         ((uint32_t)(uint8_t)q2 << 16) | ((uint32_t)(uint8_t)q3 << 24);
}

__global__ __launch_bounds__(256) void convert_kernel(
    const float* __restrict__ embed, const float* __restrict__ W,
    int8_t* __restrict__ embed_i8, float* __restrict__ scales,
    __half* __restrict__ W_h,
    float* __restrict__ spec_w, uint32_t* __restrict__ spec_ok) {
  int b = blockIdx.x;
  int wave = threadIdx.x >> 6, lane = threadIdx.x & 63;
  if (b < NWOODBLK) {
    int g = b * 256 + threadIdx.x;      // 0..16383
    int t = g >> 11;                    // spec iteration 0..7
    int i = g & (NROWS - 1);            // row
    U2 key42; key42.x = 0u; key42.y = 42u;
    U2 K = tf_subkey(key42, 0u);        // kw = K_0
    for (int j = 0; j < t; ++j) K = tf_subkey(K, 0u);
    float wn;
    bool ok = wood_try(K, (uint32_t)i, wn);
    spec_w[t * NROWS + i]  = wn;
    spec_ok[t * NROWS + i] = ok ? 1u : 0u;
  } else if (b < NWOODBLK + NBLK_W) {
    int wid = (b - NWOODBLK) * 4 + wave;          // 0..511
    size_t base = (size_t)wid * 128 + lane;
    const float4* src = (const float4*)W;
    uint2* dst = (uint2*)W_h;
    float4 a = src[base];
    float4 c = src[base + 64];
    dst[base]      = cvt4h(a);
    dst[base + 64] = cvt4h(c);
  } else {
    int wid = (b - NWOODBLK - NBLK_W) * 4 + wave; // vocab row
    if (wid < VOCAB) {
      size_t base = (size_t)wid * 128 + lane;     // float4 index
      const float4* src = (const float4*)embed;
      float4 a = src[base];
      float4 c = src[base + 64];
      float m = fmaxf(fmaxf(fmaxf(fabsf(a.x), fabsf(a.y)), fmaxf(fabsf(a.z), fabsf(a.w))),
                      fmaxf(fmaxf(fabsf(c.x), fabsf(c.y)), fmaxf(fabsf(c.z), fabsf(c.w))));
#pragma unroll
      for (int off = 1; off < 64; off <<= 1) m = fmaxf(m, __shfl_xor(m, off, 64));
      float inv   = (m > 0.0f) ? 127.0f / m : 0.0f;
      float scale = (m > 0.0f) ? m / 127.0f : 0.0f;
      uint32_t* dst = (uint32_t*)embed_i8;
      size_t b32 = (size_t)wid * 128 + lane;      // uint32 index (4 bytes each)
      dst[b32]      = quant4(a, inv);
      dst[b32 + 64] = quant4(c, inv);
      if (lane == 0) scales[wid] = scale;
    }
  }
}

// ---------------------------------------------------------------------------
// Kernel 1: blocks [0,1024): int8 gather + f32 FMA -> fp16 sums (fill-bound).
//           blocks [1024,3072): v_raw normals (VALU) — hide under gather.
// ---------------------------------------------------------------------------
__global__ __launch_bounds__(256) void gather_vr_kernel(
    const int* __restrict__ add_tok, const int* __restrict__ rem_tok,
    const int8_t* __restrict__ embed_i8, const float* __restrict__ scales,
    __half* __restrict__ sums_h, float* __restrict__ vr_buf) {
  int b = blockIdx.x;
  if (b < NROWS / 2) {
    int rb = b * 2;
    int wave = threadIdx.x >> 6;          // 0..3
    int lane = threadIdx.x & 63;
    int row = rb + (wave & 1);
    int which = wave >> 1;
    const int* tok = (which == 0 ? add_tok : rem_tok) + (size_t)row * SEQ;
    int c = lane * 8;                     // byte (elem) index within row
    float acc[8] = {};
    for (int s = 0; s < SEQ; s += 2) {
      int t0 = tok[s], t1 = tok[s + 1];
      float s0 = scales[t0], s1 = scales[t1];
      uint2 v0 = *(const uint2*)&embed_i8[(size_t)t0 * EMB + c];
      uint2 v1 = *(const uint2*)&embed_i8[(size_t)t1 * EMB + c];
      const int8_t* b0 = (const int8_t*)&v0;
      const int8_t* b1 = (const int8_t*)&v1;
#pragma unroll
      for (int j = 0; j < 8; ++j) acc[j] += s0 * (float)b0[j];
#pragma unroll
      for (int j = 0; j < 8; ++j) acc[j] += s1 * (float)b1[j];
    }
    union { __half h[8]; uint4 u; } pk;
#pragma unroll
    for (int j = 0; j < 8; ++j) pk.h[j] = __float2half(acc[j]);
    *(uint4*)&sums_h[((size_t)which * NROWS + row) * EMB + c] = pk.u;
  } else {
    // v_raw normals for row r (input-independent, key 42)
    int r = b - NROWS / 2;                // 0..2047
    U2 key42; key42.x = 0u; key42.y = 42u;
    U2 kv = tf_subkey(key42, 1u);
#pragma unroll
    for (int q = 0; q < 4; ++q) {
      int j = threadIdx.x + q * 256;
      vr_buf[(size_t)r * HID + j] =
          normal_from_bits(tf_bits32(kv, (uint32_t)(r * HID + j)));
    }
  }
}

// ---------------------------------------------------------------------------
// Kernel 2: MFMA f16 GEMM. combined[r][c] = dot(sums[c-half][r], W[c&511]).
// ---------------------------------------------------------------------------
__global__ __launch_bounds__(256) void gemm_mfma_kernel(
    const __half* __restrict__ sums_h, const __half* __restrict__ W_h,
    float* __restrict__ out) {
  int wave = threadIdx.x >> 6, lane = threadIdx.x & 63;
  int r0 = blockIdx.x * 16;
  int c0 = blockIdx.y * 256 + wave * 64;
  const __half* A = sums_h + ((c0 < 512) ? 0 : (size_t)NROWS * EMB);
  int wc0 = c0 & 511;
  int l15 = lane & 15, kg = lane >> 4;
  const _Float16* arow = (const _Float16*)&A[(size_t)(r0 + l15) * EMB];
  const _Float16* b0p  = (const _Float16*)&W_h[(size_t)(wc0 +  0 + l15) * EMB];
  const _Float16* b1p  = (const _Float16*)&W_h[(size_t)(wc0 + 16 + l15) * EMB];
  const _Float16* b2p  = (const _Float16*)&W_h[(size_t)(wc0 + 32 + l15) * EMB];
  const _Float16* b3p  = (const _Float16*)&W_h[(size_t)(wc0 + 48 + l15) * EMB];
  f32x4 acc0 = {0.f,0.f,0.f,0.f}, acc1 = acc0, acc2 = acc0, acc3 = acc0;
  for (int k0 = 0; k0 < EMB; k0 += 16) {
    int k = k0 + 4 * kg;
    f16x4 af = *(const f16x4*)&arow[k];
    f16x4 b0 = *(const f16x4*)&b0p[k];
    f16x4 b1 = *(const f16x4*)&b1p[k];
    f16x4 b2 = *(const f16x4*)&b2p[k];
    f16x4 b3 = *(const f16x4*)&b3p[k];
    acc0 = __builtin_amdgcn_mfma_f32_16x16x16f16(af, b0, acc0, 0, 0, 0);
    acc1 = __builtin_amdgcn_mfma_f32_16x16x16f16(af, b1, acc1, 0, 0, 0);
    acc2 = __builtin_amdgcn_mfma_f32_16x16x16f16(af, b2, acc2, 0, 0, 0);
    acc3 = __builtin_amdgcn_mfma_f32_16x16x16f16(af, b3, acc3, 0, 0, 0);
  }
#pragma unroll
  for (int i = 0; i < 4; ++i) {
    size_t rr = (size_t)(r0 + 4 * kg + i) * HID + c0 + l15;
    out[rr +  0] = acc0[i];
    out[rr + 16] = acc1[i];
    out[rr + 32] = acc2[i];
    out[rr + 48] = acc3[i];
  }
}

// ---------------------------------------------------------------------------
// Kernel 3: per-row finalize — mu from d_out, vr from ws, w from spec arrays.
// ---------------------------------------------------------------------------
__device__ __forceinline__ float block_reduce_sum256(float v, float* red) {
#pragma unroll
  for (int off = 32; off > 0; off >>= 1) v += __shfl_down(v, off, 64);
  if ((threadIdx.x & 63) == 0) red[threadIdx.x >> 6] = v;
  __syncthreads();
  float s = red[0] + red[1] + red[2] + red[3];
  __syncthreads();
  return s;
}

__global__ __launch_bounds__(256) void finalize_kernel(
    const float* __restrict__ spec_w, const uint32_t* __restrict__ spec_ok,
    const float* __restrict__ vr_buf, float* __restrict__ out) {
#pragma clang fp contract(off)
  __shared__ float red[4];
  int r = blockIdx.x, tid = threadIdx.x;
  U2 key42; key42.x = 0u; key42.y = 42u;
  U2 kt = tf_subkey(key42, 2u);

  float mu[4], vr[4];
#pragma unroll
  for (int q = 0; q < 4; ++q) {
    int j = tid + q * 256;
    mu[q] = out[(size_t)r * HID + j];
    vr[q] = vr_buf[(size_t)r * HID + j];
  }

  // select Wood w: first accepted speculative iteration
  float w = 0.0f;
  int found = -1;
#pragma unroll
  for (int t = 0; t < NSPEC; ++t) {
    if (found < 0 && spec_ok[t * NROWS + r]) { w = spec_w[t * NROWS + r]; found = t; }
  }
  if (found < 0) {
    U2 K = tf_subkey(key42, 0u);
    for (int j = 0; j < NSPEC; ++j) K = tf_subkey(K, 0u);
    w = wood_seq_from(K, (uint32_t)r, NSPEC);
  }
  float trand = unit_from_bits(tf_bits32(kt, (uint32_t)r)) * 0.1f;

  float ss = mu[0]*mu[0] + mu[1]*mu[1] + mu[2]*mu[2] + mu[3]*mu[3];
  ss = block_reduce_sum256(ss, red);
  float munorm = sqrtf(ss);
  float safe = fmaxf(munorm, 1e-20f);
  float muh[4];
#pragma unroll
  for (int q = 0; q < 4; ++q) muh[q] = mu[q] / safe;
  float pp = muh[0]*vr[0] + muh[1]*vr[1] + muh[2]*vr[2] + muh[3]*vr[3];
  pp = block_reduce_sum256(pp, red);
  float ortho[4];
#pragma unroll
  for (int q = 0; q < 4; ++q) ortho[q] = vr[q] - muh[q] * pp;
  float os = ortho[0]*ortho[0] + ortho[1]*ortho[1] + ortho[2]*ortho[2] + ortho[3]*ortho[3];
  os = block_reduce_sum256(os, red);
  float on = sqrtf(os);

  float sqw = sqrtf(1.0f - w * w);
  float munoise = fminf(fmaxf(munorm, 0.0f), 13.9f) + trand;
#pragma unroll
  for (int q = 0; q < 4; ++q) {
    int j = tid + q * 256;
    float v = ortho[q] / on;
    out[(size_t)r * HID + j] = (v * sqw + muh[q] * w) * munoise;
  }
}

// ---------------------------------------------------------------------------
// Fallback path kernels (f32, round-5 behavior) — used only if ws too small
// ---------------------------------------------------------------------------
__global__ __launch_bounds__(128) void gather_sum_kernel(
    const int* __restrict__ add_tok, const int* __restrict__ rem_tok,
    const float* __restrict__ embed, float* __restrict__ sums) {
  int rb = blockIdx.x * GR;
  int which = blockIdx.y;
  const int* tok = (which == 0 ? add_tok : rem_tok);
  __shared__ int t[GR][SEQ];
  for (int q = threadIdx.x; q < GR * SEQ; q += 128) {
    int rr = q >> 7, ss = q & 127;
    t[rr][ss] = tok[(size_t)(rb + rr) * SEQ + ss];
  }
  __syncthreads();
  int c = threadIdx.x * 4;
  float4 a0 = make_float4(0.f,0.f,0.f,0.f), a1 = a0, a2 = a0, a3 = a0;
  for (int s = 0; s < SEQ; ++s) {
    float4 v0 = *(const float4*)&embed[(size_t)t[0][s] * EMB + c];
    float4 v1 = *(const float4*)&embed[(size_t)t[1][s] * EMB + c];
    float4 v2 = *(const float4*)&embed[(size_t)t[2][s] * EMB + c];
    float4 v3 = *(const float4*)&embed[(size_t)t[3][s] * EMB + c];
    a0.x += v0.x; a0.y += v0.y; a0.z += v0.z; a0.w += v0.w;
    a1.x += v1.x; a1.y += v1.y; a1.z += v1.z; a1.w += v1.w;
    a2.x += v2.x; a2.y += v2.y; a2.z += v2.z; a2.w += v2.w;
    a3.x += v3.x; a3.y += v3.y; a3.z += v3.z; a3.w += v3.w;
  }
  size_t base = ((size_t)which * NROWS + rb) * EMB + c;
  *(float4*)&sums[base + 0 * EMB] = a0;
  *(float4*)&sums[base + 1 * EMB] = a1;
  *(float4*)&sums[base + 2 * EMB] = a2;
  *(float4*)&sums[base + 3 * EMB] = a3;
}

__global__ __launch_bounds__(256) void gemm_kernel(
    const float* __restrict__ sums, const float* __restrict__ W,
    float* __restrict__ out) {
  __shared__ float As[16][64];
  __shared__ float Bs[16][64];
  int r0 = blockIdx.x * 64;
  int c0 = blockIdx.y * 64;
  const float* A = sums + ((c0 < 512) ? 0 : (size_t)NROWS * EMB);
  int wc0 = c0 & 511;
  int tid = threadIdx.x;
  int tx = tid & 15, ty = tid >> 4;
  int lr = tid >> 2, lk = (tid & 3) * 4;
  float acc[4][4] = {};
  for (int k0 = 0; k0 < EMB; k0 += 16) {
    float4 av = *(const float4*)&A[(size_t)(r0 + lr) * EMB + k0 + lk];
    float4 bv = *(const float4*)&W[(size_t)(wc0 + lr) * EMB + k0 + lk];
    __syncthreads();
    As[lk + 0][lr] = av.x; As[lk + 1][lr] = av.y; As[lk + 2][lr] = av.z; As[lk + 3][lr] = av.w;
    Bs[lk + 0][lr] = bv.x; Bs[lk + 1][lr] = bv.y; Bs[lk + 2][lr] = bv.z; Bs[lk + 3][lr] = bv.w;
    __syncthreads();
#pragma unroll
    for (int kk = 0; kk < 16; ++kk) {
      float a[4], b[4];
#pragma unroll
      for (int m = 0; m < 4; ++m) a[m] = As[kk][ty * 4 + m];
#pragma unroll
      for (int n = 0; n < 4; ++n) b[n] = Bs[kk][tx * 4 + n];
#pragma unroll
      for (int m = 0; m < 4; ++m)
#pragma unroll
        for (int n = 0; n < 4; ++n) acc[m][n] += a[m] * b[n];
    }
  }
#pragma unroll
  for (int m = 0; m < 4; ++m)
#pragma unroll
    for (int n = 0; n < 4; ++n)
      out[(size_t)(r0 + ty * 4 + m) * HID + c0 + tx * 4 + n] = acc[m][n];
}

// fallback finalize with inline sequential wood + inline normals
__global__ __launch_bounds__(256) void finalize_inline_kernel(float* __restrict__ out) {
#pragma clang fp contract(off)
  __shared__ float red[4];
  int r = blockIdx.x, tid = threadIdx.x;
  U2 key42; key42.x = 0u; key42.y = 42u;
  U2 kv = tf_subkey(key42, 1u);
  U2 kt = tf_subkey(key42, 2u);

  float mu[4], vr[4];
#pragma unroll
  for (int q = 0; q < 4; ++q) {
    int j = tid + q * 256;
    mu[q] = out[(size_t)r * HID + j];
    vr[q] = normal_from_bits(tf_bits32(kv, (uint32_t)(r * HID + j)));
  }
  U2 kw = tf_subkey(key42, 0u);
  float w = wood_seq_from(kw, (uint32_t)r, 0);
  float trand = unit_from_bits(tf_bits32(kt, (uint32_t)r)) * 0.1f;

  float ss = mu[0]*mu[0] + mu[1]*mu[1] + mu[2]*mu[2] + mu[3]*mu[3];
  ss = block_reduce_sum256(ss, red);
  float munorm = sqrtf(ss);
  float safe = fmaxf(munorm, 1e-20f);
  float muh[4];
#pragma unroll
  for (int q = 0; q < 4; ++q) muh[q] = mu[q] / safe;
  float pp = muh[0]*vr[0] + muh[1]*vr[1] + muh[2]*vr[2] + muh[3]*vr[3];
  pp = block_reduce_sum256(pp, red);
  float ortho[4];
#pragma unroll
  for (int q = 0; q < 4; ++q) ortho[q] = vr[q] - muh[q] * pp;
  float os = ortho[0]*ortho[0] + ortho[1]*ortho[1] + ortho[2]*ortho[2] + ortho[3]*ortho[3];
  os = block_reduce_sum256(os, red);
  float on = sqrtf(os);

  float sqw = sqrtf(1.0f - w * w);
  float munoise = fminf(fmaxf(munorm, 0.0f), 13.9f) + trand;
#pragma unroll
  for (int q = 0; q < 4; ++q) {
    int j = tid + q * 256;
    float v = ortho[q] / on;
    out[(size_t)r * HID + j] = (v * sqw + muh[q] * w) * munoise;
  }
}

// ---------------------------------------------------------------------------
extern "C" void kernel_launch(void* const* d_in, const int* in_sizes, int n_in,
                              void* d_out, int out_size, void* d_ws, size_t ws_size,
                              hipStream_t stream) {
  const int*   add_tok = (const int*)d_in[0];
  const int*   rem_tok = (const int*)d_in[1];
  const float* embed   = (const float*)d_in[2];
  const float* W       = (const float*)d_in[3];
  float* out = (float*)d_out;

  const size_t EMBED_I8_BYTES = (size_t)VOCAB * EMB;                      // 25,731,584
  const size_t SCALE_BYTES    = (size_t)((VOCAB + 63) & ~63) * 4;         //    201,280
  const size_t W_H_BYTES      = (size_t)512 * EMB * sizeof(__half);       //    524,288
  const size_t SUMS_H_BYTES   = (size_t)2 * NROWS * EMB * sizeof(__half); //  4,194,304
  const size_t SPEC_BYTES     = (size_t)NSPEC * NROWS * 4;                //     65,536
  const size_t VR_BYTES       = (size_t)NROWS * HID * sizeof(float);      //  8,388,608
  const size_t NEED = EMBED_I8_BYTES + SCALE_BYTES + W_H_BYTES + SUMS_H_BYTES
                    + 2 * SPEC_BYTES + VR_BYTES;                          // ~39.1 MB

  if (ws_size >= NEED) {
    char* p = (char*)d_ws;
    int8_t*   embed_i8 = (int8_t*)p;   p += EMBED_I8_BYTES;
    float*    scales   = (float*)p;    p += SCALE_BYTES;
    __half*   W_h      = (__half*)p;   p += W_H_BYTES;
    __half*   sums_h   = (__half*)p;   p += SUMS_H_BYTES;
    float*    spec_w   = (float*)p;    p += SPEC_BYTES;
    uint32_t* spec_ok  = (uint32_t*)p; p += SPEC_BYTES;
    float*    vr_buf   = (float*)p;

    convert_kernel<<<NWOODBLK + NBLK_W + NBLK_E, 256, 0, stream>>>(
        embed, W, embed_i8, scales, W_h, spec_w, spec_ok);
    gather_vr_kernel<<<NROWS / 2 + NROWS, 256, 0, stream>>>(
        add_tok, rem_tok, embed_i8, scales, sums_h, vr_buf);
    gemm_mfma_kernel<<<dim3(NROWS / 16, HID / 256), 256, 0, stream>>>(sums_h, W_h, out);
    finalize_kernel<<<NROWS, 256, 0, stream>>>(spec_w, spec_ok, vr_buf, out);
  } else {
    float* sums = (float*)d_ws;
    gather_sum_kernel<<<dim3(NROWS / GR, 2), 128, 0, stream>>>(add_tok, rem_tok, embed, sums);
    gemm_kernel<<<dim3(NROWS / 64, HID / 64), 256, 0, stream>>>(sums, W, out);
    finalize_inline_kernel<<<NROWS, 256, 0, stream>>>(out);
  }
}